// Round 2
// baseline (1211.468 us; speedup 1.0000x reference)
//
#include <hip/hip_runtime.h>
#include <math.h>

#define BATCH 4
#define C 512
#define N 4096   // content spatial (64*64)
#define M 4096   // style spatial (64*64)
#define MSPLIT 4

typedef __attribute__((ext_vector_type(8))) short short8;
typedef __attribute__((ext_vector_type(8))) __bf16 bf16x8;
typedef __attribute__((ext_vector_type(4))) float f32x4;

static __device__ __forceinline__ unsigned short f2bf(float x) {
    unsigned u = __float_as_uint(x);
    u += 0x7fff + ((u >> 16) & 1);          // round-to-nearest-even
    return (unsigned short)(u >> 16);
}
static __device__ __forceinline__ float bf2f(unsigned short h) {
    return __uint_as_float(((unsigned)h) << 16);
}
static __device__ __forceinline__ f32x4 mfma_bf16(short8 a, short8 b, f32x4 c) {
    return __builtin_amdgcn_mfma_f32_16x16x32_bf16(
        __builtin_bit_cast(bf16x8, a), __builtin_bit_cast(bf16x8, b), c, 0, 0, 0);
}
// direct global->LDS DMA, 16B per lane; lds dest must be wave-uniform base
static __device__ __forceinline__ void gload16(const void* g, void* l) {
    __builtin_amdgcn_global_load_lds(
        (const __attribute__((address_space(1))) void*)g,
        (__attribute__((address_space(3))) void*)l, 16, 0, 0);
}

// ---------------------------------------------------------------------------
// K0: split W (512x512 fp32) into bf16 hi/lo, once per call
// ---------------------------------------------------------------------------
__global__ __launch_bounds__(256) void wsplit_kernel(
    const float* __restrict__ W, unsigned short* __restrict__ hi,
    unsigned short* __restrict__ lo)
{
    int i = blockIdx.x * 256 + threadIdx.x;
    float v = W[i];
    unsigned short h = f2bf(v);
    hi[i] = h;
    lo[i] = f2bf(v - bf2f(h));
}

// ---------------------------------------------------------------------------
// K1a: MFMA linear for Fq/Gt: out[n][o] (hi/lo bf16), o fastest.
// block 64n x 64o, BK=32, waves 2x2 (wave tile 32n x 32o)
// ---------------------------------------------------------------------------
__global__ __launch_bounds__(256) void linear_fg_mfma(
    const float* __restrict__ in,                     // [C][N] batch slice
    const unsigned short* __restrict__ Whi, const unsigned short* __restrict__ Wlo,
    const float* __restrict__ bias,
    unsigned short* __restrict__ out_hi, unsigned short* __restrict__ out_lo)
{
    __shared__ float in_s[32][68];                    // [k][n] fp32
    __shared__ __align__(16) unsigned short wh_s[64][40];  // [o][k]
    __shared__ __align__(16) unsigned short wl_s[64][40];
    const int tid = threadIdx.x;
    const int n0 = blockIdx.x * 64, o0 = blockIdx.y * 64;
    const int w = tid >> 6, lane = tid & 63;
    const int wrow = w >> 1, wcol = w & 1;
    const int lr = lane & 15, q = lane >> 4;
    f32x4 acc[2][2];
    #pragma unroll
    for (int i = 0; i < 2; ++i)
        #pragma unroll
        for (int j = 0; j < 2; ++j) acc[i][j] = (f32x4){0.f, 0.f, 0.f, 0.f};

    for (int kc = 0; kc < C; kc += 32) {
        __syncthreads();
        #pragma unroll
        for (int it = 0; it < 2; ++it) {
            int idx = tid + it * 256;
            int k = idx >> 4, seg = idx & 15;
            *(float4*)&in_s[k][seg * 4] =
                *(const float4*)&in[(size_t)(kc + k) * N + n0 + seg * 4];
        }
        {
            int o = tid >> 2, sg = tid & 3;
            *(float4*)&wh_s[o][sg * 8] = *(const float4*)&Whi[(size_t)(o0 + o) * 512 + kc + sg * 8];
            *(float4*)&wl_s[o][sg * 8] = *(const float4*)&Wlo[(size_t)(o0 + o) * 512 + kc + sg * 8];
        }
        __syncthreads();
        short8 ah[2], al[2], bh[2], bl[2];
        #pragma unroll
        for (int i = 0; i < 2; ++i) {
            int n = wrow * 32 + i * 16 + lr;
            #pragma unroll
            for (int j = 0; j < 8; ++j) {
                float f = in_s[q * 8 + j][n];
                unsigned short h = f2bf(f);
                ah[i][j] = (short)h;
                al[i][j] = (short)f2bf(f - bf2f(h));
            }
        }
        #pragma unroll
        for (int j = 0; j < 2; ++j) {
            int o = wcol * 32 + j * 16 + lr;
            bh[j] = *(const short8*)&wh_s[o][q * 8];
            bl[j] = *(const short8*)&wl_s[o][q * 8];
        }
        #pragma unroll
        for (int i = 0; i < 2; ++i)
            #pragma unroll
            for (int j = 0; j < 2; ++j) {
                acc[i][j] = mfma_bf16(ah[i], bh[j], acc[i][j]);
                acc[i][j] = mfma_bf16(ah[i], bl[j], acc[i][j]);
                acc[i][j] = mfma_bf16(al[i], bh[j], acc[i][j]);
            }
    }
    #pragma unroll
    for (int i = 0; i < 2; ++i)
        #pragma unroll
        for (int j = 0; j < 2; ++j) {
            int o = o0 + wcol * 32 + j * 16 + lr;
            float bo = bias[o];
            #pragma unroll
            for (int r = 0; r < 4; ++r) {
                int n = n0 + wrow * 32 + i * 16 + q * 4 + r;
                float v = acc[i][j][r] + bo;
                unsigned short h = f2bf(v);
                out_hi[(size_t)n * 512 + o] = h;
                out_lo[(size_t)n * 512 + o] = f2bf(v - bf2f(h));
            }
        }
}

// ---------------------------------------------------------------------------
// K1b: MFMA linear for V: vhT[o][m], plus precomputed v2hT/v2lT = hi/lo of
// vh^2 (restored: keeps apply_partial free of VALU squaring).
// Outputs are chunk-XOR-swizzled along m: m ^= (o&3)<<3, so apply's
// ds_read_b128 fragments are bank-conflict-reduced with linear LDS (rule:
// pre-swizzled global source + swizzled read, gload_lds dest stays linear).
// ---------------------------------------------------------------------------
__global__ __launch_bounds__(256) void linear_v_mfma(
    const float* __restrict__ in,                     // [C][M] batch slice
    const unsigned short* __restrict__ Whi, const unsigned short* __restrict__ Wlo,
    const float* __restrict__ bias,
    unsigned short* __restrict__ vhT, unsigned short* __restrict__ v2hT,
    unsigned short* __restrict__ v2lT)
{
    __shared__ float in_s[32][68];                    // [k][m]
    __shared__ __align__(16) unsigned short wh_s[64][40];
    __shared__ __align__(16) unsigned short wl_s[64][40];
    const int tid = threadIdx.x;
    const int m0 = blockIdx.x * 64, o0 = blockIdx.y * 64;
    const int w = tid >> 6, lane = tid & 63;
    const int wrow = w >> 1, wcol = w & 1;
    const int lr = lane & 15, q = lane >> 4;
    f32x4 acc[2][2];
    #pragma unroll
    for (int i = 0; i < 2; ++i)
        #pragma unroll
        for (int j = 0; j < 2; ++j) acc[i][j] = (f32x4){0.f, 0.f, 0.f, 0.f};

    for (int kc = 0; kc < C; kc += 32) {
        __syncthreads();
        #pragma unroll
        for (int it = 0; it < 2; ++it) {
            int idx = tid + it * 256;
            int k = idx >> 4, seg = idx & 15;
            *(float4*)&in_s[k][seg * 4] =
                *(const float4*)&in[(size_t)(kc + k) * N + m0 + seg * 4];
        }
        {
            int o = tid >> 2, sg = tid & 3;
            *(float4*)&wh_s[o][sg * 8] = *(const float4*)&Whi[(size_t)(o0 + o) * 512 + kc + sg * 8];
            *(float4*)&wl_s[o][sg * 8] = *(const float4*)&Wlo[(size_t)(o0 + o) * 512 + kc + sg * 8];
        }
        __syncthreads();
        short8 ah[2], al[2], bh[2], bl[2];
        #pragma unroll
        for (int i = 0; i < 2; ++i) {
            int o = wrow * 32 + i * 16 + lr;
            ah[i] = *(const short8*)&wh_s[o][q * 8];
            al[i] = *(const short8*)&wl_s[o][q * 8];
        }
        #pragma unroll
        for (int j = 0; j < 2; ++j) {
            int m = wcol * 32 + j * 16 + lr;
            #pragma unroll
            for (int t = 0; t < 8; ++t) {
                float f = in_s[q * 8 + t][m];
                unsigned short h = f2bf(f);
                bh[j][t] = (short)h;
                bl[j][t] = (short)f2bf(f - bf2f(h));
            }
        }
        #pragma unroll
        for (int i = 0; i < 2; ++i)
            #pragma unroll
            for (int j = 0; j < 2; ++j) {
                acc[i][j] = mfma_bf16(ah[i], bh[j], acc[i][j]);
                acc[i][j] = mfma_bf16(ah[i], bl[j], acc[i][j]);
                acc[i][j] = mfma_bf16(al[i], bh[j], acc[i][j]);
            }
    }
    #pragma unroll
    for (int i = 0; i < 2; ++i)
        #pragma unroll
        for (int r = 0; r < 4; ++r) {
            int o = o0 + wrow * 32 + i * 16 + q * 4 + r;
            float bo = bias[o];
            const int swz = (o & 3) << 3;
            #pragma unroll
            for (int j = 0; j < 2; ++j) {
                int m = m0 + wcol * 32 + j * 16 + lr;
                float v = acc[i][j][r] + bo;
                unsigned short vh = f2bf(v);
                float vhf = bf2f(vh);
                float vsq = vhf * vhf;
                unsigned short v2h = f2bf(vsq);
                unsigned short v2l = f2bf(vsq - bf2f(v2h));
                size_t off = (size_t)o * M + (m ^ swz);
                vhT[off] = vh;
                v2hT[off] = v2h;
                v2lT[off] = v2l;
            }
        }
}

// ---------------------------------------------------------------------------
// K2: logits MFMA: S[n][m] = Ah.BhT + Ah.BlT + Al.BhT  (hi/lo bf16 split)
// block tile 128n x 128m, BK=32, 4 waves (2x2), wave tile 64x64.
// Staging via global_load_lds (16B/lane DMA), unpadded [row][32] LDS.
// ---------------------------------------------------------------------------
__global__ __launch_bounds__(256) void logits_mfma_kernel(
    const unsigned short* __restrict__ Ah, const unsigned short* __restrict__ Al,
    const unsigned short* __restrict__ Bh, const unsigned short* __restrict__ Bl,
    float* __restrict__ S)
{
    __shared__ __align__(16) unsigned short Ah_s[128 * 32];
    __shared__ __align__(16) unsigned short Al_s[128 * 32];
    __shared__ __align__(16) unsigned short Bh_s[128 * 32];
    __shared__ __align__(16) unsigned short Bl_s[128 * 32];
    const int tid = threadIdx.x;
    const int n0 = blockIdx.y * 128, m0 = blockIdx.x * 128;
    const int w = tid >> 6, lane = tid & 63;
    const int wrow = w >> 1, wcol = w & 1;
    const int lr = lane & 15, q = lane >> 4;
    const int srow = lane >> 2, scol = (lane & 3) * 8;   // staging: 16 rows x 64B per instr
    f32x4 acc[4][4];
    #pragma unroll
    for (int i = 0; i < 4; ++i)
        #pragma unroll
        for (int j = 0; j < 4; ++j)
            acc[i][j] = (f32x4){0.f, 0.f, 0.f, 0.f};

    for (int kc = 0; kc < C; kc += 32) {
        __syncthreads();
        #pragma unroll
        for (int g2 = 0; g2 < 2; ++g2) {
            int g = w * 2 + g2;                          // chunk 0..7 (16 rows each)
            size_t ga = (size_t)(n0 + g * 16 + srow) * C + kc + scol;
            size_t gb = (size_t)(m0 + g * 16 + srow) * C + kc + scol;
            int lo = g * 512;                            // 16 rows * 32 shorts
            gload16(&Ah[ga], &Ah_s[lo]);
            gload16(&Al[ga], &Al_s[lo]);
            gload16(&Bh[gb], &Bh_s[lo]);
            gload16(&Bl[gb], &Bl_s[lo]);
        }
        __syncthreads();
        short8 ah[4], al[4], bh[4], bl[4];
        #pragma unroll
        for (int i = 0; i < 4; ++i) {
            int ro = (wrow * 64 + i * 16 + lr) * 32 + q * 8;
            int co = (wcol * 64 + i * 16 + lr) * 32 + q * 8;
            ah[i] = *(const short8*)&Ah_s[ro];
            al[i] = *(const short8*)&Al_s[ro];
            bh[i] = *(const short8*)&Bh_s[co];
            bl[i] = *(const short8*)&Bl_s[co];
        }
        #pragma unroll
        for (int i = 0; i < 4; ++i)
            #pragma unroll
            for (int j = 0; j < 4; ++j) {
                acc[i][j] = mfma_bf16(ah[i], bh[j], acc[i][j]);
                acc[i][j] = mfma_bf16(ah[i], bl[j], acc[i][j]);
                acc[i][j] = mfma_bf16(al[i], bh[j], acc[i][j]);
            }
    }
    #pragma unroll
    for (int i = 0; i < 4; ++i) {
        int nb = n0 + wrow * 64 + i * 16 + q * 4;
        #pragma unroll
        for (int j = 0; j < 4; ++j) {
            int m = m0 + wcol * 64 + j * 16 + lr;
            #pragma unroll
            for (int r = 0; r < 4; ++r)
                S[(size_t)(nb + r) * M + m] = acc[i][j][r];
        }
    }
}

// ---------------------------------------------------------------------------
// K3: row softmax -> bf16 P (chunk-XOR-swizzled: m ^= (n&3)<<3),
// rsum = sum of the ROUNDED p (consistency!)
// ---------------------------------------------------------------------------
__global__ __launch_bounds__(256) void rowstat_p_kernel(
    const float* __restrict__ S, unsigned short* __restrict__ P,
    float* __restrict__ rsum)
{
    const int n = blockIdx.x;
    const int tid = threadIdx.x;
    const float* row = S + (size_t)n * M;
    float v[16];
    #pragma unroll
    for (int i = 0; i < 16; ++i) v[i] = row[tid + i * 256];
    float lm = -INFINITY;
    #pragma unroll
    for (int i = 0; i < 16; ++i) lm = fmaxf(lm, v[i]);
    #pragma unroll
    for (int off = 32; off > 0; off >>= 1) lm = fmaxf(lm, __shfl_xor(lm, off, 64));
    __shared__ float red[4];
    __shared__ float redsum[4];
    const int wid = tid >> 6, lane = tid & 63;
    if (lane == 0) red[wid] = lm;
    __syncthreads();
    const float rm = fmaxf(fmaxf(red[0], red[1]), fmaxf(red[2], red[3]));
    float ls = 0.f;
    unsigned short* prow = P + (size_t)n * M;
    const int swz = (n & 3) << 3;
    #pragma unroll
    for (int i = 0; i < 16; ++i) {
        float p = __expf(v[i] - rm);
        unsigned short pb = f2bf(p);
        prow[(tid + i * 256) ^ swz] = pb;
        ls += bf2f(pb);
    }
    #pragma unroll
    for (int off = 32; off > 0; off >>= 1) ls += __shfl_xor(ls, off, 64);
    if (lane == 0) redsum[wid] = ls;
    __syncthreads();
    if (tid == 0) rsum[n] = redsum[0] + redsum[1] + redsum[2] + redsum[3];
}

// ---------------------------------------------------------------------------
// K4: apply partial (split-M). c-tile 128 (halves P L2-miss redundancy,
// doubles MFMA per LDS byte). Streams P/Vh/V2h/V2l all DMA-staged, all
// chunk-XOR-swizzled in global layout; fragments read with matching XOR.
// Grid (C/128, N/128, MSPLIT) = 512 blocks; partials alias dead S buffer.
// ---------------------------------------------------------------------------
__global__ __launch_bounds__(256) void apply_partial_kernel(
    const unsigned short* __restrict__ P, const unsigned short* __restrict__ VhT,
    const unsigned short* __restrict__ V2hT, const unsigned short* __restrict__ V2lT,
    float* __restrict__ accm_p, float* __restrict__ acc2_p)
{
    __shared__ __align__(16) unsigned short P_s[128 * 32];
    __shared__ __align__(16) unsigned short Vh_s[128 * 32];
    __shared__ __align__(16) unsigned short V2h_s[128 * 32];
    __shared__ __align__(16) unsigned short V2l_s[128 * 32];
    const int tid = threadIdx.x;
    const int c0 = blockIdx.x * 128, n0 = blockIdx.y * 128;
    const int z = blockIdx.z;
    const int w = tid >> 6, lane = tid & 63;
    const int wrow = w >> 1, wcol = w & 1;
    const int lr = lane & 15, q = lane >> 4;
    const int srow = lane >> 2, scol = (lane & 3) * 8;
    f32x4 accm[4][4], acc2[4][4];
    #pragma unroll
    for (int i = 0; i < 4; ++i)
        #pragma unroll
        for (int j = 0; j < 4; ++j) {
            accm[i][j] = (f32x4){0.f, 0.f, 0.f, 0.f};
            acc2[i][j] = (f32x4){0.f, 0.f, 0.f, 0.f};
        }

    const int mbeg = z * (M / MSPLIT);
    for (int mc = mbeg; mc < mbeg + M / MSPLIT; mc += 32) {
        __syncthreads();
        #pragma unroll
        for (int g2 = 0; g2 < 2; ++g2) {
            int g = w * 2 + g2;                          // chunk 0..7 (16 rows)
            size_t gp = (size_t)(n0 + g * 16 + srow) * M + mc + scol;
            size_t gv = (size_t)(c0 + g * 16 + srow) * M + mc + scol;
            int lo = g * 512;
            gload16(&P[gp],    &P_s[lo]);
            gload16(&VhT[gv],  &Vh_s[lo]);
            gload16(&V2hT[gv], &V2h_s[lo]);
            gload16(&V2lT[gv], &V2l_s[lo]);
        }
        __syncthreads();
        short8 a[4];
        #pragma unroll
        for (int i = 0; i < 4; ++i) {
            int row = wrow * 64 + i * 16 + lr;
            a[i] = *(const short8*)&P_s[row * 32 + (q * 8 ^ ((row & 3) << 3))];
        }
        #pragma unroll
        for (int j = 0; j < 4; ++j) {
            int crow = wcol * 64 + j * 16 + lr;
            int off = crow * 32 + (q * 8 ^ ((crow & 3) << 3));
            short8 bh  = *(const short8*)&Vh_s[off];
            short8 b2h = *(const short8*)&V2h_s[off];
            short8 b2l = *(const short8*)&V2l_s[off];
            #pragma unroll
            for (int i = 0; i < 4; ++i) {
                accm[i][j] = mfma_bf16(a[i], bh,  accm[i][j]);
                acc2[i][j] = mfma_bf16(a[i], b2h, acc2[i][j]);
                acc2[i][j] = mfma_bf16(a[i], b2l, acc2[i][j]);
            }
        }
    }
    const size_t pbase = (size_t)z * N * C;
    #pragma unroll
    for (int i = 0; i < 4; ++i) {
        int nb = n0 + wrow * 64 + i * 16 + q * 4;
        #pragma unroll
        for (int j = 0; j < 4; ++j) {
            int c = c0 + wcol * 64 + j * 16 + lr;
            #pragma unroll
            for (int r = 0; r < 4; ++r) {
                size_t off = pbase + (size_t)(nb + r) * C + c;
                accm_p[off] = accm[i][j][r];
                acc2_p[off] = acc2[i][j][r];
            }
        }
    }
}

// ---------------------------------------------------------------------------
// K4b: combine partials -> mean/std (fp32). One float4 of c per thread.
// ---------------------------------------------------------------------------
__global__ __launch_bounds__(256) void combine_kernel(
    const float* __restrict__ accm_p, const float* __restrict__ acc2_p,
    const float* __restrict__ rsum, float* __restrict__ meanw,
    float* __restrict__ stdw)
{
    const size_t idx = ((size_t)blockIdx.x * 256 + threadIdx.x) * 4;
    const int n = (int)(idx >> 9);        // /C (C=512)
    const float inv = 1.0f / rsum[n];
    float sm[4] = {0.f, 0.f, 0.f, 0.f}, s2[4] = {0.f, 0.f, 0.f, 0.f};
    #pragma unroll
    for (int z = 0; z < MSPLIT; ++z) {
        float4 a = *(const float4*)&accm_p[(size_t)z * N * C + idx];
        float4 b = *(const float4*)&acc2_p[(size_t)z * N * C + idx];
        sm[0] += a.x; sm[1] += a.y; sm[2] += a.z; sm[3] += a.w;
        s2[0] += b.x; s2[1] += b.y; s2[2] += b.z; s2[3] += b.w;
    }
    float4 mnv, sdv;
    float* mp = (float*)&mnv;
    float* sp = (float*)&sdv;
    #pragma unroll
    for (int k = 0; k < 4; ++k) {
        float mn = sm[k] * inv;
        float m2 = s2[k] * inv;
        mp[k] = mn;
        sp[k] = sqrtf(fmaxf(m2 - mn * mn, 0.f));
    }
    *(float4*)&meanw[idx] = mnv;
    *(float4*)&stdw[idx]  = sdv;
}

// ---------------------------------------------------------------------------
// K5: instance-norm stats per channel (fp32)
// ---------------------------------------------------------------------------
__global__ __launch_bounds__(256) void mvn_kernel(
    const float* __restrict__ content, float* __restrict__ mu, float* __restrict__ rstd)
{
    const int c = blockIdx.x;
    const int tid = threadIdx.x;
    const float* row = content + (size_t)c * N;
    float s = 0.f, ss = 0.f;
    for (int i = tid; i < N; i += 256) {
        float v = row[i];
        s += v;
        ss = fmaf(v, v, ss);
    }
    #pragma unroll
    for (int off = 32; off > 0; off >>= 1) {
        s  += __shfl_xor(s,  off, 64);
        ss += __shfl_xor(ss, off, 64);
    }
    __shared__ float rs[4], rss[4];
    const int wid = tid >> 6, lane = tid & 63;
    if (lane == 0) { rs[wid] = s; rss[wid] = ss; }
    __syncthreads();
    if (tid == 0) {
        float st = rs[0] + rs[1] + rs[2] + rs[3];
        float sst = rss[0] + rss[1] + rss[2] + rss[3];
        float m = st / (float)N;
        float var = (sst - st * st / (float)N) / (float)(N - 1);
        mu[c] = m;
        rstd[c] = rsqrtf(var + 1e-5f);
    }
}

// ---------------------------------------------------------------------------
// K6: final combine (fp32)
// ---------------------------------------------------------------------------
__global__ __launch_bounds__(256) void final_kernel(
    const float* __restrict__ content, const float* __restrict__ meanw,
    const float* __restrict__ stdw, const float* __restrict__ mu,
    const float* __restrict__ rstd, float* __restrict__ out)
{
    __shared__ float mn_s[32][33], sd_s[32][33];
    const int tid = threadIdx.x;
    const int n0 = blockIdx.x * 32;
    const int c0 = blockIdx.y * 32;
    const int tx = tid & 31, ty = tid >> 5;
    #pragma unroll
    for (int i = 0; i < 4; ++i) {
        int n = ty + i * 8;
        mn_s[tx][n] = meanw[(size_t)(n0 + n) * C + c0 + tx];
        sd_s[tx][n] = stdw [(size_t)(n0 + n) * C + c0 + tx];
    }
    __syncthreads();
    #pragma unroll
    for (int i = 0; i < 4; ++i) {
        int c = ty + i * 8;
        float m = mu[c0 + c], r = rstd[c0 + c];
        size_t off = (size_t)(c0 + c) * N + n0 + tx;
        float x = content[off];
        out[off] = sd_s[c][tx] * (x - m) * r + mn_s[c][tx];
    }
}

// ---------------------------------------------------------------------------
extern "C" void kernel_launch(void* const* d_in, const int* in_sizes, int n_in,
                              void* d_out, int out_size, void* d_ws, size_t ws_size,
                              hipStream_t stream)
{
    const float* content = (const float*)d_in[0];
    const float* style   = (const float*)d_in[1];
    const float* ckey    = (const float*)d_in[2];
    const float* skey    = (const float*)d_in[3];
    const float* Wf      = (const float*)d_in[4];
    const float* bf      = (const float*)d_in[5];
    const float* Wg      = (const float*)d_in[6];
    const float* bg      = (const float*)d_in[7];
    const float* Wh      = (const float*)d_in[8];
    const float* bh      = (const float*)d_in[9];
    float* out = (float*)d_out;

    const size_t sz_w  = (size_t)512 * 512 * 2;      // one W half
    const size_t sz_S  = (size_t)N * M * 4;          // 64 MB (aliased by partials)
    const size_t sz_FG = (size_t)N * C * 2;
    const size_t sz_P  = (size_t)N * M * 2;
    const size_t sz_V  = (size_t)C * M * 2;

    char* p = (char*)d_ws;
    auto alloc = [&](size_t bytes) {
        char* r = p;
        p += (bytes + 255) & ~(size_t)255;
        return r;
    };
    unsigned short* WfH = (unsigned short*)alloc(sz_w);
    unsigned short* WfL = (unsigned short*)alloc(sz_w);
    unsigned short* WgH = (unsigned short*)alloc(sz_w);
    unsigned short* WgL = (unsigned short*)alloc(sz_w);
    unsigned short* WhH = (unsigned short*)alloc(sz_w);
    unsigned short* WhL = (unsigned short*)alloc(sz_w);
    float* S = (float*)alloc(sz_S);                  // also: partial accm/acc2
    unsigned short* Fh = (unsigned short*)alloc(sz_FG);
    unsigned short* Fl = (unsigned short*)alloc(sz_FG);
    unsigned short* Gh = (unsigned short*)alloc(sz_FG);
    unsigned short* Gl = (unsigned short*)alloc(sz_FG);
    unsigned short* P    = (unsigned short*)alloc(sz_P);
    unsigned short* VhT  = (unsigned short*)alloc(sz_V);
    unsigned short* V2hT = (unsigned short*)alloc(sz_V);
    unsigned short* V2lT = (unsigned short*)alloc(sz_V);
    float* rsum  = (float*)alloc((size_t)N * 4);
    float* meanw = (float*)alloc((size_t)N * C * 4);
    float* stdw  = (float*)alloc((size_t)N * C * 4);
    float* mu    = (float*)alloc((size_t)C * 4);
    float* rstd  = (float*)alloc((size_t)C * 4);

    // partials alias S (dead between rowstat and next batch's logits):
    // accm_p = MSPLIT*N*C floats, acc2_p = MSPLIT*N*C floats = exactly N*M
    float* accm_p = S;
    float* acc2_p = S + (size_t)MSPLIT * N * C;

    wsplit_kernel<<<dim3(1024), 256, 0, stream>>>(Wf, WfH, WfL);
    wsplit_kernel<<<dim3(1024), 256, 0, stream>>>(Wg, WgH, WgL);
    wsplit_kernel<<<dim3(1024), 256, 0, stream>>>(Wh, WhH, WhL);

    for (int b = 0; b < BATCH; ++b) {
        const size_t fo = (size_t)b * C * N;
        linear_fg_mfma<<<dim3(N / 64, C / 64), 256, 0, stream>>>(ckey + fo, WfH, WfL, bf, Fh, Fl);
        linear_fg_mfma<<<dim3(M / 64, C / 64), 256, 0, stream>>>(skey + fo, WgH, WgL, bg, Gh, Gl);
        linear_v_mfma<<<dim3(M / 64, C / 64), 256, 0, stream>>>(style + fo, WhH, WhL, bh,
                                                                VhT, V2hT, V2lT);
        logits_mfma_kernel<<<dim3(M / 128, N / 128), 256, 0, stream>>>(Fh, Fl, Gh, Gl, S);
        rowstat_p_kernel<<<dim3(N), 256, 0, stream>>>(S, P, rsum);
        apply_partial_kernel<<<dim3(C / 128, N / 128, MSPLIT), 256, 0, stream>>>(
            P, VhT, V2hT, V2lT, accm_p, acc2_p);
        combine_kernel<<<dim3(N * C / 1024), 256, 0, stream>>>(
            accm_p, acc2_p, rsum, meanw, stdw);
        mvn_kernel<<<dim3(C), 256, 0, stream>>>(content + fo, mu, rstd);
        final_kernel<<<dim3(N / 32, C / 32), 256, 0, stream>>>(
            content + fo, meanw, stdw, mu, rstd, out + fo);
    }
}

// Round 3
// 1194.911 us; speedup vs baseline: 1.0139x; 1.0139x over previous
//
#include <hip/hip_runtime.h>
#include <math.h>

#define BATCH 4
#define C 512
#define N 4096   // content spatial (64*64)
#define M 4096   // style spatial (64*64)
#define MSPLIT 4

typedef __attribute__((ext_vector_type(8))) short short8;
typedef __attribute__((ext_vector_type(8))) __bf16 bf16x8;
typedef __attribute__((ext_vector_type(4))) float f32x4;

static __device__ __forceinline__ unsigned short f2bf(float x) {
    unsigned u = __float_as_uint(x);
    u += 0x7fff + ((u >> 16) & 1);          // round-to-nearest-even
    return (unsigned short)(u >> 16);
}
static __device__ __forceinline__ float bf2f(unsigned short h) {
    return __uint_as_float(((unsigned)h) << 16);
}
static __device__ __forceinline__ f32x4 mfma_bf16(short8 a, short8 b, f32x4 c) {
    return __builtin_amdgcn_mfma_f32_16x16x32_bf16(
        __builtin_bit_cast(bf16x8, a), __builtin_bit_cast(bf16x8, b), c, 0, 0, 0);
}
// direct global->LDS DMA, 16B per lane; lds dest must be wave-uniform base
static __device__ __forceinline__ void gload16(const void* g, void* l) {
    __builtin_amdgcn_global_load_lds(
        (const __attribute__((address_space(1))) void*)g,
        (__attribute__((address_space(3))) void*)l, 16, 0, 0);
}

// ---------------------------------------------------------------------------
// K0: split W (512x512 fp32) into bf16 hi/lo, once per call
// ---------------------------------------------------------------------------
__global__ __launch_bounds__(256) void wsplit_kernel(
    const float* __restrict__ W, unsigned short* __restrict__ hi,
    unsigned short* __restrict__ lo)
{
    int i = blockIdx.x * 256 + threadIdx.x;
    float v = W[i];
    unsigned short h = f2bf(v);
    hi[i] = h;
    lo[i] = f2bf(v - bf2f(h));
}

// ---------------------------------------------------------------------------
// K1a: MFMA linear for Fq/Gt: out[n][o] (hi/lo bf16), o fastest.
// block 64n x 64o, BK=32, waves 2x2 (wave tile 32n x 32o)
// ---------------------------------------------------------------------------
__global__ __launch_bounds__(256) void linear_fg_mfma(
    const float* __restrict__ in,                     // [C][N] batch slice
    const unsigned short* __restrict__ Whi, const unsigned short* __restrict__ Wlo,
    const float* __restrict__ bias,
    unsigned short* __restrict__ out_hi, unsigned short* __restrict__ out_lo)
{
    __shared__ float in_s[32][68];                    // [k][n] fp32
    __shared__ __align__(16) unsigned short wh_s[64][40];  // [o][k]
    __shared__ __align__(16) unsigned short wl_s[64][40];
    const int tid = threadIdx.x;
    const int n0 = blockIdx.x * 64, o0 = blockIdx.y * 64;
    const int w = tid >> 6, lane = tid & 63;
    const int wrow = w >> 1, wcol = w & 1;
    const int lr = lane & 15, q = lane >> 4;
    f32x4 acc[2][2];
    #pragma unroll
    for (int i = 0; i < 2; ++i)
        #pragma unroll
        for (int j = 0; j < 2; ++j) acc[i][j] = (f32x4){0.f, 0.f, 0.f, 0.f};

    for (int kc = 0; kc < C; kc += 32) {
        __syncthreads();
        #pragma unroll
        for (int it = 0; it < 2; ++it) {
            int idx = tid + it * 256;
            int k = idx >> 4, seg = idx & 15;
            *(float4*)&in_s[k][seg * 4] =
                *(const float4*)&in[(size_t)(kc + k) * N + n0 + seg * 4];
        }
        {
            int o = tid >> 2, sg = tid & 3;
            *(float4*)&wh_s[o][sg * 8] = *(const float4*)&Whi[(size_t)(o0 + o) * 512 + kc + sg * 8];
            *(float4*)&wl_s[o][sg * 8] = *(const float4*)&Wlo[(size_t)(o0 + o) * 512 + kc + sg * 8];
        }
        __syncthreads();
        short8 ah[2], al[2], bh[2], bl[2];
        #pragma unroll
        for (int i = 0; i < 2; ++i) {
            int n = wrow * 32 + i * 16 + lr;
            #pragma unroll
            for (int j = 0; j < 8; ++j) {
                float f = in_s[q * 8 + j][n];
                unsigned short h = f2bf(f);
                ah[i][j] = (short)h;
                al[i][j] = (short)f2bf(f - bf2f(h));
            }
        }
        #pragma unroll
        for (int j = 0; j < 2; ++j) {
            int o = wcol * 32 + j * 16 + lr;
            bh[j] = *(const short8*)&wh_s[o][q * 8];
            bl[j] = *(const short8*)&wl_s[o][q * 8];
        }
        #pragma unroll
        for (int i = 0; i < 2; ++i)
            #pragma unroll
            for (int j = 0; j < 2; ++j) {
                acc[i][j] = mfma_bf16(ah[i], bh[j], acc[i][j]);
                acc[i][j] = mfma_bf16(ah[i], bl[j], acc[i][j]);
                acc[i][j] = mfma_bf16(al[i], bh[j], acc[i][j]);
            }
    }
    #pragma unroll
    for (int i = 0; i < 2; ++i)
        #pragma unroll
        for (int j = 0; j < 2; ++j) {
            int o = o0 + wcol * 32 + j * 16 + lr;
            float bo = bias[o];
            #pragma unroll
            for (int r = 0; r < 4; ++r) {
                int n = n0 + wrow * 32 + i * 16 + q * 4 + r;
                float v = acc[i][j][r] + bo;
                unsigned short h = f2bf(v);
                out_hi[(size_t)n * 512 + o] = h;
                out_lo[(size_t)n * 512 + o] = f2bf(v - bf2f(h));
            }
        }
}

// ---------------------------------------------------------------------------
// K1b: MFMA linear for V: vhT[o][m], plus precomputed v2hT/v2lT = hi/lo of
// vh^2 (keeps apply_partial free of VALU squaring — r1 lesson).
// Outputs chunk-XOR-swizzled along m: m ^= (o&3)<<3 (pre-swizzled global
// source + swizzled ds_read, LDS stays linear for gload_lds).
// ---------------------------------------------------------------------------
__global__ __launch_bounds__(256) void linear_v_mfma(
    const float* __restrict__ in,                     // [C][M] batch slice
    const unsigned short* __restrict__ Whi, const unsigned short* __restrict__ Wlo,
    const float* __restrict__ bias,
    unsigned short* __restrict__ vhT, unsigned short* __restrict__ v2hT,
    unsigned short* __restrict__ v2lT)
{
    __shared__ float in_s[32][68];                    // [k][m]
    __shared__ __align__(16) unsigned short wh_s[64][40];
    __shared__ __align__(16) unsigned short wl_s[64][40];
    const int tid = threadIdx.x;
    const int m0 = blockIdx.x * 64, o0 = blockIdx.y * 64;
    const int w = tid >> 6, lane = tid & 63;
    const int wrow = w >> 1, wcol = w & 1;
    const int lr = lane & 15, q = lane >> 4;
    f32x4 acc[2][2];
    #pragma unroll
    for (int i = 0; i < 2; ++i)
        #pragma unroll
        for (int j = 0; j < 2; ++j) acc[i][j] = (f32x4){0.f, 0.f, 0.f, 0.f};

    for (int kc = 0; kc < C; kc += 32) {
        __syncthreads();
        #pragma unroll
        for (int it = 0; it < 2; ++it) {
            int idx = tid + it * 256;
            int k = idx >> 4, seg = idx & 15;
            *(float4*)&in_s[k][seg * 4] =
                *(const float4*)&in[(size_t)(kc + k) * N + m0 + seg * 4];
        }
        {
            int o = tid >> 2, sg = tid & 3;
            *(float4*)&wh_s[o][sg * 8] = *(const float4*)&Whi[(size_t)(o0 + o) * 512 + kc + sg * 8];
            *(float4*)&wl_s[o][sg * 8] = *(const float4*)&Wlo[(size_t)(o0 + o) * 512 + kc + sg * 8];
        }
        __syncthreads();
        short8 ah[2], al[2], bh[2], bl[2];
        #pragma unroll
        for (int i = 0; i < 2; ++i) {
            int o = wrow * 32 + i * 16 + lr;
            ah[i] = *(const short8*)&wh_s[o][q * 8];
            al[i] = *(const short8*)&wl_s[o][q * 8];
        }
        #pragma unroll
        for (int j = 0; j < 2; ++j) {
            int m = wcol * 32 + j * 16 + lr;
            #pragma unroll
            for (int t = 0; t < 8; ++t) {
                float f = in_s[q * 8 + t][m];
                unsigned short h = f2bf(f);
                bh[j][t] = (short)h;
                bl[j][t] = (short)f2bf(f - bf2f(h));
            }
        }
        #pragma unroll
        for (int i = 0; i < 2; ++i)
            #pragma unroll
            for (int j = 0; j < 2; ++j) {
                acc[i][j] = mfma_bf16(ah[i], bh[j], acc[i][j]);
                acc[i][j] = mfma_bf16(ah[i], bl[j], acc[i][j]);
                acc[i][j] = mfma_bf16(al[i], bh[j], acc[i][j]);
            }
    }
    #pragma unroll
    for (int i = 0; i < 2; ++i)
        #pragma unroll
        for (int r = 0; r < 4; ++r) {
            int o = o0 + wrow * 32 + i * 16 + q * 4 + r;
            float bo = bias[o];
            const int swz = (o & 3) << 3;
            #pragma unroll
            for (int j = 0; j < 2; ++j) {
                int m = m0 + wcol * 32 + j * 16 + lr;
                float v = acc[i][j][r] + bo;
                unsigned short vh = f2bf(v);
                float vhf = bf2f(vh);
                float vsq = vhf * vhf;
                unsigned short v2h = f2bf(vsq);
                unsigned short v2l = f2bf(vsq - bf2f(v2h));
                size_t off = (size_t)o * M + (m ^ swz);
                vhT[off] = vh;
                v2hT[off] = v2h;
                v2lT[off] = v2l;
            }
        }
}

// ---------------------------------------------------------------------------
// K2: logits MFMA: S[n][m] = Ah.BhT + Ah.BlT + Al.BhT  (hi/lo bf16 split)
// block tile 128n x 128m, BK=32, 4 waves (2x2), wave tile 64x64.
// Staging via global_load_lds (16B/lane DMA), unpadded [row][32] LDS.
// ---------------------------------------------------------------------------
__global__ __launch_bounds__(256) void logits_mfma_kernel(
    const unsigned short* __restrict__ Ah, const unsigned short* __restrict__ Al,
    const unsigned short* __restrict__ Bh, const unsigned short* __restrict__ Bl,
    float* __restrict__ S)
{
    __shared__ __align__(16) unsigned short Ah_s[128 * 32];
    __shared__ __align__(16) unsigned short Al_s[128 * 32];
    __shared__ __align__(16) unsigned short Bh_s[128 * 32];
    __shared__ __align__(16) unsigned short Bl_s[128 * 32];
    const int tid = threadIdx.x;
    const int n0 = blockIdx.y * 128, m0 = blockIdx.x * 128;
    const int w = tid >> 6, lane = tid & 63;
    const int wrow = w >> 1, wcol = w & 1;
    const int lr = lane & 15, q = lane >> 4;
    const int srow = lane >> 2, scol = (lane & 3) * 8;   // staging: 16 rows x 64B per instr
    f32x4 acc[4][4];
    #pragma unroll
    for (int i = 0; i < 4; ++i)
        #pragma unroll
        for (int j = 0; j < 4; ++j)
            acc[i][j] = (f32x4){0.f, 0.f, 0.f, 0.f};

    for (int kc = 0; kc < C; kc += 32) {
        __syncthreads();
        #pragma unroll
        for (int g2 = 0; g2 < 2; ++g2) {
            int g = w * 2 + g2;                          // chunk 0..7 (16 rows each)
            size_t ga = (size_t)(n0 + g * 16 + srow) * C + kc + scol;
            size_t gb = (size_t)(m0 + g * 16 + srow) * C + kc + scol;
            int lo = g * 512;                            // 16 rows * 32 shorts
            gload16(&Ah[ga], &Ah_s[lo]);
            gload16(&Al[ga], &Al_s[lo]);
            gload16(&Bh[gb], &Bh_s[lo]);
            gload16(&Bl[gb], &Bl_s[lo]);
        }
        __syncthreads();
        short8 ah[4], al[4], bh[4], bl[4];
        #pragma unroll
        for (int i = 0; i < 4; ++i) {
            int ro = (wrow * 64 + i * 16 + lr) * 32 + q * 8;
            int co = (wcol * 64 + i * 16 + lr) * 32 + q * 8;
            ah[i] = *(const short8*)&Ah_s[ro];
            al[i] = *(const short8*)&Al_s[ro];
            bh[i] = *(const short8*)&Bh_s[co];
            bl[i] = *(const short8*)&Bl_s[co];
        }
        #pragma unroll
        for (int i = 0; i < 4; ++i)
            #pragma unroll
            for (int j = 0; j < 4; ++j) {
                acc[i][j] = mfma_bf16(ah[i], bh[j], acc[i][j]);
                acc[i][j] = mfma_bf16(ah[i], bl[j], acc[i][j]);
                acc[i][j] = mfma_bf16(al[i], bh[j], acc[i][j]);
            }
    }
    #pragma unroll
    for (int i = 0; i < 4; ++i) {
        int nb = n0 + wrow * 64 + i * 16 + q * 4;
        #pragma unroll
        for (int j = 0; j < 4; ++j) {
            int m = m0 + wcol * 64 + j * 16 + lr;
            #pragma unroll
            for (int r = 0; r < 4; ++r)
                S[(size_t)(nb + r) * M + m] = acc[i][j][r];
        }
    }
}

// ---------------------------------------------------------------------------
// K3: row softmax -> bf16 P (chunk-XOR-swizzled: m ^= (n&3)<<3),
// rsum = sum of the ROUNDED p (consistency!)
// ---------------------------------------------------------------------------
__global__ __launch_bounds__(256) void rowstat_p_kernel(
    const float* __restrict__ S, unsigned short* __restrict__ P,
    float* __restrict__ rsum)
{
    const int n = blockIdx.x;
    const int tid = threadIdx.x;
    const float* row = S + (size_t)n * M;
    float v[16];
    #pragma unroll
    for (int i = 0; i < 16; ++i) v[i] = row[tid + i * 256];
    float lm = -INFINITY;
    #pragma unroll
    for (int i = 0; i < 16; ++i) lm = fmaxf(lm, v[i]);
    #pragma unroll
    for (int off = 32; off > 0; off >>= 1) lm = fmaxf(lm, __shfl_xor(lm, off, 64));
    __shared__ float red[4];
    __shared__ float redsum[4];
    const int wid = tid >> 6, lane = tid & 63;
    if (lane == 0) red[wid] = lm;
    __syncthreads();
    const float rm = fmaxf(fmaxf(red[0], red[1]), fmaxf(red[2], red[3]));
    float ls = 0.f;
    unsigned short* prow = P + (size_t)n * M;
    const int swz = (n & 3) << 3;
    #pragma unroll
    for (int i = 0; i < 16; ++i) {
        float p = __expf(v[i] - rm);
        unsigned short pb = f2bf(p);
        prow[(tid + i * 256) ^ swz] = pb;
        ls += bf2f(pb);
    }
    #pragma unroll
    for (int off = 32; off > 0; off >>= 1) ls += __shfl_xor(ls, off, 64);
    if (lane == 0) redsum[wid] = ls;
    __syncthreads();
    if (tid == 0) rsum[n] = redsum[0] + redsum[1] + redsum[2] + redsum[3];
}

// ---------------------------------------------------------------------------
// K4: apply partial (split-M). c-tile 64 (r1's occupancy), DMA staging,
// precomputed V2 streams (r0's low VALU), PLUS 2-phase double-buffer:
// stage(t+1) is issued before compute(t); __syncthreads' implicit vmcnt(0)
// drains it one full compute phase later. Grid (C/64, N/128, MSPLIT)=1024.
// ---------------------------------------------------------------------------
__global__ __launch_bounds__(256) void apply_partial_kernel(
    const unsigned short* __restrict__ P, const unsigned short* __restrict__ VhT,
    const unsigned short* __restrict__ V2hT, const unsigned short* __restrict__ V2lT,
    float* __restrict__ accm_p, float* __restrict__ acc2_p)
{
    __shared__ __align__(16) unsigned short P_s[2][128 * 32];
    __shared__ __align__(16) unsigned short Vh_s[2][64 * 32];
    __shared__ __align__(16) unsigned short V2h_s[2][64 * 32];
    __shared__ __align__(16) unsigned short V2l_s[2][64 * 32];
    const int tid = threadIdx.x;
    const int c0 = blockIdx.x * 64, n0 = blockIdx.y * 128;
    const int z = blockIdx.z;
    const int w = tid >> 6, lane = tid & 63;
    const int wrow = w >> 1, wcol = w & 1;
    const int lr = lane & 15, q = lane >> 4;
    const int srow = lane >> 2, scol = (lane & 3) * 8;
    f32x4 accm[4][2], acc2[4][2];
    #pragma unroll
    for (int i = 0; i < 4; ++i)
        #pragma unroll
        for (int j = 0; j < 2; ++j) {
            accm[i][j] = (f32x4){0.f, 0.f, 0.f, 0.f};
            acc2[i][j] = (f32x4){0.f, 0.f, 0.f, 0.f};
        }

    const int mbeg = z * (M / MSPLIT);
    const size_t vrow = (size_t)(c0 + w * 16 + srow) * M + scol;

    auto STAGE = [&](int buf, int mc) {
        #pragma unroll
        for (int g2 = 0; g2 < 2; ++g2) {
            int g = w * 2 + g2;                          // P chunk 0..7 (16 rows)
            gload16(&P[(size_t)(n0 + g * 16 + srow) * M + mc + scol], &P_s[buf][g * 512]);
        }
        gload16(&VhT [vrow + mc], &Vh_s[buf][w * 512]);
        gload16(&V2hT[vrow + mc], &V2h_s[buf][w * 512]);
        gload16(&V2lT[vrow + mc], &V2l_s[buf][w * 512]);
    };

    const int NT = (M / MSPLIT) / 32;
    STAGE(0, mbeg);
    int cur = 0;
    for (int t = 0; t < NT; ++t) {
        __syncthreads();                                 // vmcnt(0): buf[cur] ready; buf[cur^1] reads done
        if (t + 1 < NT) STAGE(cur ^ 1, mbeg + (t + 1) * 32);
        short8 a[4], bh[2], b2h[2], b2l[2];
        #pragma unroll
        for (int i = 0; i < 4; ++i) {
            int row = wrow * 64 + i * 16 + lr;
            a[i] = *(const short8*)&P_s[cur][row * 32 + (q * 8 ^ ((row & 3) << 3))];
        }
        #pragma unroll
        for (int j = 0; j < 2; ++j) {
            int crow = wcol * 32 + j * 16 + lr;
            int off = crow * 32 + (q * 8 ^ ((crow & 3) << 3));
            bh[j]  = *(const short8*)&Vh_s[cur][off];
            b2h[j] = *(const short8*)&V2h_s[cur][off];
            b2l[j] = *(const short8*)&V2l_s[cur][off];
        }
        #pragma unroll
        for (int i = 0; i < 4; ++i)
            #pragma unroll
            for (int j = 0; j < 2; ++j) {
                accm[i][j] = mfma_bf16(a[i], bh[j],  accm[i][j]);
                acc2[i][j] = mfma_bf16(a[i], b2h[j], acc2[i][j]);
                acc2[i][j] = mfma_bf16(a[i], b2l[j], acc2[i][j]);
            }
        cur ^= 1;
    }
    const size_t pbase = (size_t)z * N * C;
    #pragma unroll
    for (int i = 0; i < 4; ++i) {
        int nb = n0 + wrow * 64 + i * 16 + q * 4;
        #pragma unroll
        for (int j = 0; j < 2; ++j) {
            int c = c0 + wcol * 32 + j * 16 + lr;
            #pragma unroll
            for (int r = 0; r < 4; ++r) {
                size_t off = pbase + (size_t)(nb + r) * C + c;
                accm_p[off] = accm[i][j][r];
                acc2_p[off] = acc2[i][j][r];
            }
        }
    }
}

// ---------------------------------------------------------------------------
// K4b: combine partials -> mean/std (fp32). One float4 of c per thread.
// ---------------------------------------------------------------------------
__global__ __launch_bounds__(256) void combine_kernel(
    const float* __restrict__ accm_p, const float* __restrict__ acc2_p,
    const float* __restrict__ rsum, float* __restrict__ meanw,
    float* __restrict__ stdw)
{
    const size_t idx = ((size_t)blockIdx.x * 256 + threadIdx.x) * 4;
    const int n = (int)(idx >> 9);        // /C (C=512)
    const float inv = 1.0f / rsum[n];
    float sm[4] = {0.f, 0.f, 0.f, 0.f}, s2[4] = {0.f, 0.f, 0.f, 0.f};
    #pragma unroll
    for (int z = 0; z < MSPLIT; ++z) {
        float4 a = *(const float4*)&accm_p[(size_t)z * N * C + idx];
        float4 b = *(const float4*)&acc2_p[(size_t)z * N * C + idx];
        sm[0] += a.x; sm[1] += a.y; sm[2] += a.z; sm[3] += a.w;
        s2[0] += b.x; s2[1] += b.y; s2[2] += b.z; s2[3] += b.w;
    }
    float4 mnv, sdv;
    float* mp = (float*)&mnv;
    float* sp = (float*)&sdv;
    #pragma unroll
    for (int k = 0; k < 4; ++k) {
        float mn = sm[k] * inv;
        float m2 = s2[k] * inv;
        mp[k] = mn;
        sp[k] = sqrtf(fmaxf(m2 - mn * mn, 0.f));
    }
    *(float4*)&meanw[idx] = mnv;
    *(float4*)&stdw[idx]  = sdv;
}

// ---------------------------------------------------------------------------
// K5: instance-norm stats per channel (fp32)
// ---------------------------------------------------------------------------
__global__ __launch_bounds__(256) void mvn_kernel(
    const float* __restrict__ content, float* __restrict__ mu, float* __restrict__ rstd)
{
    const int c = blockIdx.x;
    const int tid = threadIdx.x;
    const float* row = content + (size_t)c * N;
    float s = 0.f, ss = 0.f;
    for (int i = tid; i < N; i += 256) {
        float v = row[i];
        s += v;
        ss = fmaf(v, v, ss);
    }
    #pragma unroll
    for (int off = 32; off > 0; off >>= 1) {
        s  += __shfl_xor(s,  off, 64);
        ss += __shfl_xor(ss, off, 64);
    }
    __shared__ float rs[4], rss[4];
    const int wid = tid >> 6, lane = tid & 63;
    if (lane == 0) { rs[wid] = s; rss[wid] = ss; }
    __syncthreads();
    if (tid == 0) {
        float st = rs[0] + rs[1] + rs[2] + rs[3];
        float sst = rss[0] + rss[1] + rss[2] + rss[3];
        float m = st / (float)N;
        float var = (sst - st * st / (float)N) / (float)(N - 1);
        mu[c] = m;
        rstd[c] = rsqrtf(var + 1e-5f);
    }
}

// ---------------------------------------------------------------------------
// K6: final combine (fp32)
// ---------------------------------------------------------------------------
__global__ __launch_bounds__(256) void final_kernel(
    const float* __restrict__ content, const float* __restrict__ meanw,
    const float* __restrict__ stdw, const float* __restrict__ mu,
    const float* __restrict__ rstd, float* __restrict__ out)
{
    __shared__ float mn_s[32][33], sd_s[32][33];
    const int tid = threadIdx.x;
    const int n0 = blockIdx.x * 32;
    const int c0 = blockIdx.y * 32;
    const int tx = tid & 31, ty = tid >> 5;
    #pragma unroll
    for (int i = 0; i < 4; ++i) {
        int n = ty + i * 8;
        mn_s[tx][n] = meanw[(size_t)(n0 + n) * C + c0 + tx];
        sd_s[tx][n] = stdw [(size_t)(n0 + n) * C + c0 + tx];
    }
    __syncthreads();
    #pragma unroll
    for (int i = 0; i < 4; ++i) {
        int c = ty + i * 8;
        float m = mu[c0 + c], r = rstd[c0 + c];
        size_t off = (size_t)(c0 + c) * N + n0 + tx;
        float x = content[off];
        out[off] = sd_s[c][tx] * (x - m) * r + mn_s[c][tx];
    }
}

// ---------------------------------------------------------------------------
extern "C" void kernel_launch(void* const* d_in, const int* in_sizes, int n_in,
                              void* d_out, int out_size, void* d_ws, size_t ws_size,
                              hipStream_t stream)
{
    const float* content = (const float*)d_in[0];
    const float* style   = (const float*)d_in[1];
    const float* ckey    = (const float*)d_in[2];
    const float* skey    = (const float*)d_in[3];
    const float* Wf      = (const float*)d_in[4];
    const float* bf      = (const float*)d_in[5];
    const float* Wg      = (const float*)d_in[6];
    const float* bg      = (const float*)d_in[7];
    const float* Wh      = (const float*)d_in[8];
    const float* bh      = (const float*)d_in[9];
    float* out = (float*)d_out;

    const size_t sz_w  = (size_t)512 * 512 * 2;      // one W half
    const size_t sz_S  = (size_t)N * M * 4;          // 64 MB (aliased by partials)
    const size_t sz_FG = (size_t)N * C * 2;
    const size_t sz_P  = (size_t)N * M * 2;
    const size_t sz_V  = (size_t)C * M * 2;

    char* p = (char*)d_ws;
    auto alloc = [&](size_t bytes) {
        char* r = p;
        p += (bytes + 255) & ~(size_t)255;
        return r;
    };
    unsigned short* WfH = (unsigned short*)alloc(sz_w);
    unsigned short* WfL = (unsigned short*)alloc(sz_w);
    unsigned short* WgH = (unsigned short*)alloc(sz_w);
    unsigned short* WgL = (unsigned short*)alloc(sz_w);
    unsigned short* WhH = (unsigned short*)alloc(sz_w);
    unsigned short* WhL = (unsigned short*)alloc(sz_w);
    float* S = (float*)alloc(sz_S);                  // also: partial accm/acc2
    unsigned short* Fh = (unsigned short*)alloc(sz_FG);
    unsigned short* Fl = (unsigned short*)alloc(sz_FG);
    unsigned short* Gh = (unsigned short*)alloc(sz_FG);
    unsigned short* Gl = (unsigned short*)alloc(sz_FG);
    unsigned short* P    = (unsigned short*)alloc(sz_P);
    unsigned short* VhT  = (unsigned short*)alloc(sz_V);
    unsigned short* V2hT = (unsigned short*)alloc(sz_V);
    unsigned short* V2lT = (unsigned short*)alloc(sz_V);
    float* rsum  = (float*)alloc((size_t)N * 4);
    float* meanw = (float*)alloc((size_t)N * C * 4);
    float* stdw  = (float*)alloc((size_t)N * C * 4);
    float* mu    = (float*)alloc((size_t)C * 4);
    float* rstd  = (float*)alloc((size_t)C * 4);

    // partials alias S (dead between rowstat and next batch's logits):
    // accm_p = MSPLIT*N*C floats, acc2_p = MSPLIT*N*C floats = exactly N*M
    float* accm_p = S;
    float* acc2_p = S + (size_t)MSPLIT * N * C;

    wsplit_kernel<<<dim3(1024), 256, 0, stream>>>(Wf, WfH, WfL);
    wsplit_kernel<<<dim3(1024), 256, 0, stream>>>(Wg, WgH, WgL);
    wsplit_kernel<<<dim3(1024), 256, 0, stream>>>(Wh, WhH, WhL);

    for (int b = 0; b < BATCH; ++b) {
        const size_t fo = (size_t)b * C * N;
        linear_fg_mfma<<<dim3(N / 64, C / 64), 256, 0, stream>>>(ckey + fo, WfH, WfL, bf, Fh, Fl);
        linear_fg_mfma<<<dim3(M / 64, C / 64), 256, 0, stream>>>(skey + fo, WgH, WgL, bg, Gh, Gl);
        linear_v_mfma<<<dim3(M / 64, C / 64), 256, 0, stream>>>(style + fo, WhH, WhL, bh,
                                                                VhT, V2hT, V2lT);
        logits_mfma_kernel<<<dim3(M / 128, N / 128), 256, 0, stream>>>(Fh, Fl, Gh, Gl, S);
        rowstat_p_kernel<<<dim3(N), 256, 0, stream>>>(S, P, rsum);
        apply_partial_kernel<<<dim3(C / 64, N / 128, MSPLIT), 256, 0, stream>>>(
            P, VhT, V2hT, V2lT, accm_p, acc2_p);
        combine_kernel<<<dim3(N * C / 1024), 256, 0, stream>>>(
            accm_p, acc2_p, rsum, meanw, stdw);
        mvn_kernel<<<dim3(C), 256, 0, stream>>>(content + fo, mu, rstd);
        final_kernel<<<dim3(N / 32, C / 32), 256, 0, stream>>>(
            content + fo, meanw, stdw, mu, rstd, out + fo);
    }
}

// Round 4
// 1116.046 us; speedup vs baseline: 1.0855x; 1.0707x over previous
//
#include <hip/hip_runtime.h>
#include <math.h>

#define BATCH 4
#define C 512
#define N 4096   // content spatial (64*64)
#define M 4096   // style spatial (64*64)
#define MSPLIT 4
#define GK 1536  // triple-K for logits: [hi|hi|lo] x [hi|lo|hi]
#define GNT 48   // GK / 32

typedef __attribute__((ext_vector_type(8))) short short8;
typedef __attribute__((ext_vector_type(8))) __bf16 bf16x8;
typedef __attribute__((ext_vector_type(4))) float f32x4;
typedef __attribute__((ext_vector_type(4))) unsigned int uint4v;

static __device__ __forceinline__ unsigned short f2bf(float x) {
    unsigned u = __float_as_uint(x);
    u += 0x7fff + ((u >> 16) & 1);          // round-to-nearest-even
    return (unsigned short)(u >> 16);
}
static __device__ __forceinline__ float bf2f(unsigned short h) {
    return __uint_as_float(((unsigned)h) << 16);
}
static __device__ __forceinline__ f32x4 mfma_bf16(short8 a, short8 b, f32x4 c) {
    return __builtin_amdgcn_mfma_f32_16x16x32_bf16(
        __builtin_bit_cast(bf16x8, a), __builtin_bit_cast(bf16x8, b), c, 0, 0, 0);
}
// direct global->LDS DMA, 16B per lane; lds dest must be wave-uniform base
static __device__ __forceinline__ void gload16(const void* g, void* l) {
    __builtin_amdgcn_global_load_lds(
        (const __attribute__((address_space(1))) void*)g,
        (__attribute__((address_space(3))) void*)l, 16, 0, 0);
}
// packed f32->bf16 (RTNE), 2 elems/op
static __device__ __forceinline__ unsigned cvt_pk_bf16(float a, float b) {
    unsigned r;
    asm("v_cvt_pk_bf16_f32 %0, %1, %2" : "=v"(r) : "v"(a), "v"(b));
    return r;
}

// ---------------------------------------------------------------------------
// K0: split W (512x512 fp32) into bf16 hi/lo, once per call
// ---------------------------------------------------------------------------
__global__ __launch_bounds__(256) void wsplit_kernel(
    const float* __restrict__ W, unsigned short* __restrict__ hi,
    unsigned short* __restrict__ lo)
{
    int i = blockIdx.x * 256 + threadIdx.x;
    float v = W[i];
    unsigned short h = f2bf(v);
    hi[i] = h;
    lo[i] = f2bf(v - bf2f(h));
}

// ---------------------------------------------------------------------------
// K1a: MFMA linear for Fq/Gt, emitting TRIPLE-K rows of width GK=1536.
// hi value stored to dstH1 and dstH2 segments, lo to dstL segment
// (pointers pre-offset by seg*512): F' = [hi|hi|lo], G' = [hi|lo|hi].
// ---------------------------------------------------------------------------
__global__ __launch_bounds__(256) void linear_fg_mfma(
    const float* __restrict__ in,                     // [C][N] batch slice
    const unsigned short* __restrict__ Whi, const unsigned short* __restrict__ Wlo,
    const float* __restrict__ bias,
    unsigned short* __restrict__ dstH1, unsigned short* __restrict__ dstH2,
    unsigned short* __restrict__ dstL)
{
    __shared__ float in_s[32][68];                    // [k][n] fp32
    __shared__ __align__(16) unsigned short wh_s[64][40];  // [o][k]
    __shared__ __align__(16) unsigned short wl_s[64][40];
    const int tid = threadIdx.x;
    const int n0 = blockIdx.x * 64, o0 = blockIdx.y * 64;
    const int w = tid >> 6, lane = tid & 63;
    const int wrow = w >> 1, wcol = w & 1;
    const int lr = lane & 15, q = lane >> 4;
    f32x4 acc[2][2];
    #pragma unroll
    for (int i = 0; i < 2; ++i)
        #pragma unroll
        for (int j = 0; j < 2; ++j) acc[i][j] = (f32x4){0.f, 0.f, 0.f, 0.f};

    for (int kc = 0; kc < C; kc += 32) {
        __syncthreads();
        #pragma unroll
        for (int it = 0; it < 2; ++it) {
            int idx = tid + it * 256;
            int k = idx >> 4, seg = idx & 15;
            *(float4*)&in_s[k][seg * 4] =
                *(const float4*)&in[(size_t)(kc + k) * N + n0 + seg * 4];
        }
        {
            int o = tid >> 2, sg = tid & 3;
            *(float4*)&wh_s[o][sg * 8] = *(const float4*)&Whi[(size_t)(o0 + o) * 512 + kc + sg * 8];
            *(float4*)&wl_s[o][sg * 8] = *(const float4*)&Wlo[(size_t)(o0 + o) * 512 + kc + sg * 8];
        }
        __syncthreads();
        short8 ah[2], al[2], bh[2], bl[2];
        #pragma unroll
        for (int i = 0; i < 2; ++i) {
            int n = wrow * 32 + i * 16 + lr;
            #pragma unroll
            for (int j = 0; j < 8; ++j) {
                float f = in_s[q * 8 + j][n];
                unsigned short h = f2bf(f);
                ah[i][j] = (short)h;
                al[i][j] = (short)f2bf(f - bf2f(h));
            }
        }
        #pragma unroll
        for (int j = 0; j < 2; ++j) {
            int o = wcol * 32 + j * 16 + lr;
            bh[j] = *(const short8*)&wh_s[o][q * 8];
            bl[j] = *(const short8*)&wl_s[o][q * 8];
        }
        #pragma unroll
        for (int i = 0; i < 2; ++i)
            #pragma unroll
            for (int j = 0; j < 2; ++j) {
                acc[i][j] = mfma_bf16(ah[i], bh[j], acc[i][j]);
                acc[i][j] = mfma_bf16(ah[i], bl[j], acc[i][j]);
                acc[i][j] = mfma_bf16(al[i], bh[j], acc[i][j]);
            }
    }
    #pragma unroll
    for (int i = 0; i < 2; ++i)
        #pragma unroll
        for (int j = 0; j < 2; ++j) {
            int o = o0 + wcol * 32 + j * 16 + lr;
            float bo = bias[o];
            #pragma unroll
            for (int r = 0; r < 4; ++r) {
                int n = n0 + wrow * 32 + i * 16 + q * 4 + r;
                float v = acc[i][j][r] + bo;
                unsigned short h = f2bf(v);
                unsigned short l = f2bf(v - bf2f(h));
                size_t row = (size_t)n * GK + o;
                dstH1[row] = h;
                dstH2[row] = h;
                dstL[row]  = l;
            }
        }
}

// ---------------------------------------------------------------------------
// K1b: MFMA linear for V: vhT[o][m] only (r1-proven: apply squares in-reg)
// ---------------------------------------------------------------------------
__global__ __launch_bounds__(256) void linear_v_mfma(
    const float* __restrict__ in,                     // [C][M] batch slice
    const unsigned short* __restrict__ Whi, const unsigned short* __restrict__ Wlo,
    const float* __restrict__ bias,
    unsigned short* __restrict__ vhT)
{
    __shared__ float in_s[32][68];                    // [k][m]
    __shared__ __align__(16) unsigned short wh_s[64][40];
    __shared__ __align__(16) unsigned short wl_s[64][40];
    const int tid = threadIdx.x;
    const int m0 = blockIdx.x * 64, o0 = blockIdx.y * 64;
    const int w = tid >> 6, lane = tid & 63;
    const int wrow = w >> 1, wcol = w & 1;
    const int lr = lane & 15, q = lane >> 4;
    f32x4 acc[2][2];
    #pragma unroll
    for (int i = 0; i < 2; ++i)
        #pragma unroll
        for (int j = 0; j < 2; ++j) acc[i][j] = (f32x4){0.f, 0.f, 0.f, 0.f};

    for (int kc = 0; kc < C; kc += 32) {
        __syncthreads();
        #pragma unroll
        for (int it = 0; it < 2; ++it) {
            int idx = tid + it * 256;
            int k = idx >> 4, seg = idx & 15;
            *(float4*)&in_s[k][seg * 4] =
                *(const float4*)&in[(size_t)(kc + k) * N + m0 + seg * 4];
        }
        {
            int o = tid >> 2, sg = tid & 3;
            *(float4*)&wh_s[o][sg * 8] = *(const float4*)&Whi[(size_t)(o0 + o) * 512 + kc + sg * 8];
            *(float4*)&wl_s[o][sg * 8] = *(const float4*)&Wlo[(size_t)(o0 + o) * 512 + kc + sg * 8];
        }
        __syncthreads();
        short8 ah[2], al[2], bh[2], bl[2];
        #pragma unroll
        for (int i = 0; i < 2; ++i) {
            int o = wrow * 32 + i * 16 + lr;
            ah[i] = *(const short8*)&wh_s[o][q * 8];
            al[i] = *(const short8*)&wl_s[o][q * 8];
        }
        #pragma unroll
        for (int j = 0; j < 2; ++j) {
            int m = wcol * 32 + j * 16 + lr;
            #pragma unroll
            for (int t = 0; t < 8; ++t) {
                float f = in_s[q * 8 + t][m];
                unsigned short h = f2bf(f);
                bh[j][t] = (short)h;
                bl[j][t] = (short)f2bf(f - bf2f(h));
            }
        }
        #pragma unroll
        for (int i = 0; i < 2; ++i)
            #pragma unroll
            for (int j = 0; j < 2; ++j) {
                acc[i][j] = mfma_bf16(ah[i], bh[j], acc[i][j]);
                acc[i][j] = mfma_bf16(ah[i], bl[j], acc[i][j]);
                acc[i][j] = mfma_bf16(al[i], bh[j], acc[i][j]);
            }
    }
    #pragma unroll
    for (int i = 0; i < 2; ++i)
        #pragma unroll
        for (int r = 0; r < 4; ++r) {
            int o = o0 + wrow * 32 + i * 16 + q * 4 + r;
            float bo = bias[o];
            #pragma unroll
            for (int j = 0; j < 2; ++j) {
                int m = m0 + wcol * 32 + j * 16 + lr;
                float v = acc[i][j][r] + bo;
                vhT[(size_t)o * M + m] = f2bf(v);
            }
        }
}

// ---------------------------------------------------------------------------
// K2: logits as PLAIN bf16 GEMM: S = A'[N][GK] . B'[M][GK]^T  (fp32 out)
// 256x256 tile, BK=32, 8 waves (2x4), wave tile 128x64.
// TRIPLE-buffered LDS (96KB), prefetch distance 2 -> counted vmcnt(4)
// (never 0 until last tile). Raw s_barrier + sched_barrier fences,
// setprio around MFMA clusters, both-sides XOR swizzle (chunk ^= (row>>1)&3)
// via inverse-swizzled gload SOURCE + swizzled ds_read (LDS stays linear).
// ---------------------------------------------------------------------------
__global__ __launch_bounds__(512) void logits_mfma_kernel(
    const unsigned short* __restrict__ A, const unsigned short* __restrict__ B,
    float* __restrict__ S)
{
    __shared__ __align__(16) unsigned short A_s[3][256 * 32];
    __shared__ __align__(16) unsigned short B_s[3][256 * 32];
    const int tid = threadIdx.x;
    // bijective XCD chunk swizzle: 256 blocks, 8 XCDs -> 32 contiguous per XCD
    const int orig = blockIdx.x;
    const int sw = (orig & 7) * 32 + (orig >> 3);
    const int m0 = (sw & 15) * 256, n0 = (sw >> 4) * 256;
    const int w = tid >> 6, lane = tid & 63;
    const int wm = w >> 2, wn = w & 3;                // 2 (n) x 4 (m) waves
    const int lr = lane & 15, q = lane >> 4;
    // fragment read offset (shorts) incl. swizzle: sel = (row>>1)&3 = (lr>>1)&3
    const int koff = lr * 32 + ((q ^ ((lr >> 1) & 3)) * 8);
    const int abase = (wm * 128) * 32 + koff;         // + i*512
    const int bbase = (wn * 64) * 32 + koff;          // + j*512
    // stage addressing: lane covers (srow = lane>>2, chunk = lane&3);
    // source pre-swizzled: chunk' = chunk ^ ((srow>>1)&3) = (lane&3)^((lane>>3)&3)
    const int srow_l = lane >> 2;
    const int schunk = (lane & 3) ^ ((lane >> 3) & 3);
    size_t gA[2], gB[2];
    #pragma unroll
    for (int r = 0; r < 2; ++r) {
        int trow = w * 32 + r * 16 + srow_l;          // row within 256-tile
        gA[r] = (size_t)(n0 + trow) * GK + (size_t)schunk * 8;
        gB[r] = (size_t)(m0 + trow) * GK + (size_t)schunk * 8;
    }

    f32x4 acc[8][4];
    #pragma unroll
    for (int i = 0; i < 8; ++i)
        #pragma unroll
        for (int j = 0; j < 4; ++j) acc[i][j] = (f32x4){0.f, 0.f, 0.f, 0.f};

    #define STAGE_A(buf, t)                                            \
        { _Pragma("unroll")                                            \
          for (int r = 0; r < 2; ++r)                                  \
              gload16(A + gA[r] + (size_t)(t) * 32,                    \
                      &A_s[buf][(w * 2 + r) * 512]); }
    #define STAGE_B(buf, t)                                            \
        { _Pragma("unroll")                                            \
          for (int r = 0; r < 2; ++r)                                  \
              gload16(B + gB[r] + (size_t)(t) * 32,                    \
                      &B_s[buf][(w * 2 + r) * 512]); }

    STAGE_A(0, 0); STAGE_B(0, 0);
    STAGE_A(1, 1); STAGE_B(1, 1);

    int bc = 0;                                       // t % 3
    for (int t = 0; t < GNT; ++t) {
        if (t < GNT - 1) asm volatile("s_waitcnt vmcnt(4)" ::: "memory");
        else             asm volatile("s_waitcnt vmcnt(0)" ::: "memory");
        __builtin_amdgcn_s_barrier();
        __builtin_amdgcn_sched_barrier(0);
        const unsigned short* As = A_s[bc];
        const unsigned short* Bs = B_s[bc];
        int bn = bc + 2; if (bn >= 3) bn -= 3;
        short8 bfr[4], afr[4];
        #pragma unroll
        for (int j = 0; j < 4; ++j) bfr[j] = *(const short8*)&Bs[bbase + j * 512];
        #pragma unroll
        for (int i = 0; i < 4; ++i) afr[i] = *(const short8*)&As[abase + i * 512];
        if (t + 2 < GNT) STAGE_A(bn, t + 2);
        __builtin_amdgcn_s_barrier();
        __builtin_amdgcn_sched_barrier(0);
        __builtin_amdgcn_s_setprio(1);
        #pragma unroll
        for (int i = 0; i < 4; ++i)
            #pragma unroll
            for (int j = 0; j < 4; ++j)
                acc[i][j] = mfma_bf16(afr[i], bfr[j], acc[i][j]);
        __builtin_amdgcn_s_setprio(0);
        __builtin_amdgcn_s_barrier();
        __builtin_amdgcn_sched_barrier(0);
        #pragma unroll
        for (int i = 0; i < 4; ++i) afr[i] = *(const short8*)&As[abase + (i + 4) * 512];
        if (t + 2 < GNT) STAGE_B(bn, t + 2);
        __builtin_amdgcn_s_barrier();
        __builtin_amdgcn_sched_barrier(0);
        __builtin_amdgcn_s_setprio(1);
        #pragma unroll
        for (int i = 0; i < 4; ++i)
            #pragma unroll
            for (int j = 0; j < 4; ++j)
                acc[i + 4][j] = mfma_bf16(afr[i], bfr[j], acc[i + 4][j]);
        __builtin_amdgcn_s_setprio(0);
        bc += 1; if (bc >= 3) bc -= 3;
    }
    #undef STAGE_A
    #undef STAGE_B

    #pragma unroll
    for (int i = 0; i < 8; ++i) {
        int n = n0 + wm * 128 + i * 16 + q * 4;
        #pragma unroll
        for (int j = 0; j < 4; ++j) {
            int m = m0 + wn * 64 + j * 16 + lr;
            #pragma unroll
            for (int r = 0; r < 4; ++r)
                S[(size_t)(n + r) * M + m] = acc[i][j][r];
        }
    }
}

// ---------------------------------------------------------------------------
// K3: row softmax -> bf16 P, rsum = sum of the ROUNDED p (consistency!)
// ---------------------------------------------------------------------------
__global__ __launch_bounds__(256) void rowstat_p_kernel(
    const float* __restrict__ S, unsigned short* __restrict__ P,
    float* __restrict__ rsum)
{
    const int n = blockIdx.x;
    const int tid = threadIdx.x;
    const float* row = S + (size_t)n * M;
    float v[16];
    #pragma unroll
    for (int i = 0; i < 16; ++i) v[i] = row[tid + i * 256];
    float lm = -INFINITY;
    #pragma unroll
    for (int i = 0; i < 16; ++i) lm = fmaxf(lm, v[i]);
    #pragma unroll
    for (int off = 32; off > 0; off >>= 1) lm = fmaxf(lm, __shfl_xor(lm, off, 64));
    __shared__ float red[4];
    __shared__ float redsum[4];
    const int wid = tid >> 6, lane = tid & 63;
    if (lane == 0) red[wid] = lm;
    __syncthreads();
    const float rm = fmaxf(fmaxf(red[0], red[1]), fmaxf(red[2], red[3]));
    float ls = 0.f;
    unsigned short* prow = P + (size_t)n * M;
    #pragma unroll
    for (int i = 0; i < 16; ++i) {
        float p = __expf(v[i] - rm);
        unsigned short pb = f2bf(p);
        prow[tid + i * 256] = pb;
        ls += bf2f(pb);
    }
    #pragma unroll
    for (int off = 32; off > 0; off >>= 1) ls += __shfl_xor(ls, off, 64);
    if (lane == 0) redsum[wid] = ls;
    __syncthreads();
    if (tid == 0) rsum[n] = redsum[0] + redsum[1] + redsum[2] + redsum[3];
}

// ---------------------------------------------------------------------------
// K4: apply partial (split-M) — r1-proven config: P + VhT streams only,
// in-register V^2 hi/lo from Vh fragment, serial stage/compute, DMA staging.
// Grid (C/64, N/128, MSPLIT); partials alias the dead S buffer.
// ---------------------------------------------------------------------------
__global__ __launch_bounds__(256) void apply_partial_kernel(
    const unsigned short* __restrict__ P, const unsigned short* __restrict__ VhT,
    float* __restrict__ accm_p, float* __restrict__ acc2_p)
{
    __shared__ __align__(16) unsigned short P_s[128 * 32];
    __shared__ __align__(16) unsigned short Vh_s[64 * 32];
    const int tid = threadIdx.x;
    const int c0 = blockIdx.x * 64, n0 = blockIdx.y * 128;
    const int z = blockIdx.z;
    const int w = tid >> 6, lane = tid & 63;
    const int wrow = w >> 1, wcol = w & 1;
    const int lr = lane & 15, q = lane >> 4;
    const int srow = lane >> 2, scol = (lane & 3) * 8;
    f32x4 accm[4][2], acc2[4][2];
    #pragma unroll
    for (int i = 0; i < 4; ++i)
        #pragma unroll
        for (int j = 0; j < 2; ++j) {
            accm[i][j] = (f32x4){0.f, 0.f, 0.f, 0.f};
            acc2[i][j] = (f32x4){0.f, 0.f, 0.f, 0.f};
        }

    const int mbeg = z * (M / MSPLIT);
    for (int mc = mbeg; mc < mbeg + M / MSPLIT; mc += 32) {
        __syncthreads();
        #pragma unroll
        for (int g2 = 0; g2 < 2; ++g2) {
            int g = w * 2 + g2;                          // P chunk 0..7
            gload16(&P[(size_t)(n0 + g * 16 + srow) * M + mc + scol], &P_s[g * 512]);
        }
        gload16(&VhT[(size_t)(c0 + w * 16 + srow) * M + mc + scol], &Vh_s[w * 512]);
        __syncthreads();
        short8 a[4], bh[2], b2h[2], b2l[2];
        #pragma unroll
        for (int i = 0; i < 4; ++i)
            a[i] = *(const short8*)&P_s[(wrow * 64 + i * 16 + lr) * 32 + q * 8];
        #pragma unroll
        for (int j = 0; j < 2; ++j) {
            bh[j] = *(const short8*)&Vh_s[(wcol * 32 + j * 16 + lr) * 32 + q * 8];
            uint4v u = __builtin_bit_cast(uint4v, bh[j]);
            uint4v hv, lv;
            #pragma unroll
            for (int t = 0; t < 4; ++t) {
                float v0 = __uint_as_float(u[t] << 16);
                float v1 = __uint_as_float(u[t] & 0xffff0000u);
                float s0 = v0 * v0, s1 = v1 * v1;
                unsigned hh = cvt_pk_bf16(s0, s1);
                float r0 = s0 - __uint_as_float(hh << 16);
                float r1 = s1 - __uint_as_float(hh & 0xffff0000u);
                hv[t] = hh;
                lv[t] = cvt_pk_bf16(r0, r1);
            }
            b2h[j] = __builtin_bit_cast(short8, hv);
            b2l[j] = __builtin_bit_cast(short8, lv);
        }
        #pragma unroll
        for (int i = 0; i < 4; ++i)
            #pragma unroll
            for (int j = 0; j < 2; ++j) {
                accm[i][j] = mfma_bf16(a[i], bh[j],  accm[i][j]);
                acc2[i][j] = mfma_bf16(a[i], b2h[j], acc2[i][j]);
                acc2[i][j] = mfma_bf16(a[i], b2l[j], acc2[i][j]);
            }
    }
    const size_t pbase = (size_t)z * N * C;
    #pragma unroll
    for (int i = 0; i < 4; ++i) {
        int nb = n0 + wrow * 64 + i * 16 + q * 4;
        #pragma unroll
        for (int j = 0; j < 2; ++j) {
            int c = c0 + wcol * 32 + j * 16 + lr;
            #pragma unroll
            for (int r = 0; r < 4; ++r) {
                size_t off = pbase + (size_t)(nb + r) * C + c;
                accm_p[off] = accm[i][j][r];
                acc2_p[off] = acc2[i][j][r];
            }
        }
    }
}

// ---------------------------------------------------------------------------
// K4b: combine partials -> mean/std (fp32). One float4 of c per thread.
// ---------------------------------------------------------------------------
__global__ __launch_bounds__(256) void combine_kernel(
    const float* __restrict__ accm_p, const float* __restrict__ acc2_p,
    const float* __restrict__ rsum, float* __restrict__ meanw,
    float* __restrict__ stdw)
{
    const size_t idx = ((size_t)blockIdx.x * 256 + threadIdx.x) * 4;
    const int n = (int)(idx >> 9);        // /C (C=512)
    const float inv = 1.0f / rsum[n];
    float sm[4] = {0.f, 0.f, 0.f, 0.f}, s2[4] = {0.f, 0.f, 0.f, 0.f};
    #pragma unroll
    for (int z = 0; z < MSPLIT; ++z) {
        float4 a = *(const float4*)&accm_p[(size_t)z * N * C + idx];
        float4 b = *(const float4*)&acc2_p[(size_t)z * N * C + idx];
        sm[0] += a.x; sm[1] += a.y; sm[2] += a.z; sm[3] += a.w;
        s2[0] += b.x; s2[1] += b.y; s2[2] += b.z; s2[3] += b.w;
    }
    float4 mnv, sdv;
    float* mp = (float*)&mnv;
    float* sp = (float*)&sdv;
    #pragma unroll
    for (int k = 0; k < 4; ++k) {
        float mn = sm[k] * inv;
        float m2 = s2[k] * inv;
        mp[k] = mn;
        sp[k] = sqrtf(fmaxf(m2 - mn * mn, 0.f));
    }
    *(float4*)&meanw[idx] = mnv;
    *(float4*)&stdw[idx]  = sdv;
}

// ---------------------------------------------------------------------------
// K5: instance-norm stats per channel (fp32)
// ---------------------------------------------------------------------------
__global__ __launch_bounds__(256) void mvn_kernel(
    const float* __restrict__ content, float* __restrict__ mu, float* __restrict__ rstd)
{
    const int c = blockIdx.x;
    const int tid = threadIdx.x;
    const float* row = content + (size_t)c * N;
    float s = 0.f, ss = 0.f;
    for (int i = tid; i < N; i += 256) {
        float v = row[i];
        s += v;
        ss = fmaf(v, v, ss);
    }
    #pragma unroll
    for (int off = 32; off > 0; off >>= 1) {
        s  += __shfl_xor(s,  off, 64);
        ss += __shfl_xor(ss, off, 64);
    }
    __shared__ float rs[4], rss[4];
    const int wid = tid >> 6, lane = tid & 63;
    if (lane == 0) { rs[wid] = s; rss[wid] = ss; }
    __syncthreads();
    if (tid == 0) {
        float st = rs[0] + rs[1] + rs[2] + rs[3];
        float sst = rss[0] + rss[1] + rss[2] + rss[3];
        float m = st / (float)N;
        float var = (sst - st * st / (float)N) / (float)(N - 1);
        mu[c] = m;
        rstd[c] = rsqrtf(var + 1e-5f);
    }
}

// ---------------------------------------------------------------------------
// K6: final combine (fp32)
// ---------------------------------------------------------------------------
__global__ __launch_bounds__(256) void final_kernel(
    const float* __restrict__ content, const float* __restrict__ meanw,
    const float* __restrict__ stdw, const float* __restrict__ mu,
    const float* __restrict__ rstd, float* __restrict__ out)
{
    __shared__ float mn_s[32][33], sd_s[32][33];
    const int tid = threadIdx.x;
    const int n0 = blockIdx.x * 32;
    const int c0 = blockIdx.y * 32;
    const int tx = tid & 31, ty = tid >> 5;
    #pragma unroll
    for (int i = 0; i < 4; ++i) {
        int n = ty + i * 8;
        mn_s[tx][n] = meanw[(size_t)(n0 + n) * C + c0 + tx];
        sd_s[tx][n] = stdw [(size_t)(n0 + n) * C + c0 + tx];
    }
    __syncthreads();
    #pragma unroll
    for (int i = 0; i < 4; ++i) {
        int c = ty + i * 8;
        float m = mu[c0 + c], r = rstd[c0 + c];
        size_t off = (size_t)(c0 + c) * N + n0 + tx;
        float x = content[off];
        out[off] = sd_s[c][tx] * (x - m) * r + mn_s[c][tx];
    }
}

// ---------------------------------------------------------------------------
extern "C" void kernel_launch(void* const* d_in, const int* in_sizes, int n_in,
                              void* d_out, int out_size, void* d_ws, size_t ws_size,
                              hipStream_t stream)
{
    const float* content = (const float*)d_in[0];
    const float* style   = (const float*)d_in[1];
    const float* ckey    = (const float*)d_in[2];
    const float* skey    = (const float*)d_in[3];
    const float* Wf      = (const float*)d_in[4];
    const float* bf      = (const float*)d_in[5];
    const float* Wg      = (const float*)d_in[6];
    const float* bg      = (const float*)d_in[7];
    const float* Wh      = (const float*)d_in[8];
    const float* bh      = (const float*)d_in[9];
    float* out = (float*)d_out;

    const size_t sz_w  = (size_t)512 * 512 * 2;      // one W half
    const size_t sz_S  = (size_t)N * M * 4;          // 64 MB (aliased by partials)
    const size_t sz_FG = (size_t)N * GK * 2;         // 12 MB triple-K
    const size_t sz_P  = (size_t)N * M * 2;
    const size_t sz_V  = (size_t)C * M * 2;

    char* p = (char*)d_ws;
    auto alloc = [&](size_t bytes) {
        char* r = p;
        p += (bytes + 255) & ~(size_t)255;
        return r;
    };
    unsigned short* WfH = (unsigned short*)alloc(sz_w);
    unsigned short* WfL = (unsigned short*)alloc(sz_w);
    unsigned short* WgH = (unsigned short*)alloc(sz_w);
    unsigned short* WgL = (unsigned short*)alloc(sz_w);
    unsigned short* WhH = (unsigned short*)alloc(sz_w);
    unsigned short* WhL = (unsigned short*)alloc(sz_w);
    float* S = (float*)alloc(sz_S);                  // also: partial accm/acc2
    unsigned short* Fp = (unsigned short*)alloc(sz_FG);   // [n][GK] = [hi|hi|lo]
    unsigned short* Gp = (unsigned short*)alloc(sz_FG);   // [m][GK] = [hi|lo|hi]
    unsigned short* P    = (unsigned short*)alloc(sz_P);
    unsigned short* VhT  = (unsigned short*)alloc(sz_V);
    float* rsum  = (float*)alloc((size_t)N * 4);
    float* meanw = (float*)alloc((size_t)N * C * 4);
    float* stdw  = (float*)alloc((size_t)N * C * 4);
    float* mu    = (float*)alloc((size_t)C * 4);
    float* rstd  = (float*)alloc((size_t)C * 4);

    // partials alias S (dead between rowstat and next batch's logits)
    float* accm_p = S;
    float* acc2_p = S + (size_t)MSPLIT * N * C;

    wsplit_kernel<<<dim3(1024), 256, 0, stream>>>(Wf, WfH, WfL);
    wsplit_kernel<<<dim3(1024), 256, 0, stream>>>(Wg, WgH, WgL);
    wsplit_kernel<<<dim3(1024), 256, 0, stream>>>(Wh, WhH, WhL);

    for (int b = 0; b < BATCH; ++b) {
        const size_t fo = (size_t)b * C * N;
        linear_fg_mfma<<<dim3(N / 64, C / 64), 256, 0, stream>>>(
            ckey + fo, WfH, WfL, bf, Fp, Fp + 512, Fp + 1024);
        linear_fg_mfma<<<dim3(M / 64, C / 64), 256, 0, stream>>>(
            skey + fo, WgH, WgL, bg, Gp, Gp + 1024, Gp + 512);
        linear_v_mfma<<<dim3(M / 64, C / 64), 256, 0, stream>>>(
            style + fo, WhH, WhL, bh, VhT);
        logits_mfma_kernel<<<dim3(256), 512, 0, stream>>>(Fp, Gp, S);
        rowstat_p_kernel<<<dim3(N), 256, 0, stream>>>(S, P, rsum);
        apply_partial_kernel<<<dim3(C / 64, N / 128, MSPLIT), 256, 0, stream>>>(
            P, VhT, accm_p, acc2_p);
        combine_kernel<<<dim3(N * C / 1024), 256, 0, stream>>>(
            accm_p, acc2_p, rsum, meanw, stdw);
        mvn_kernel<<<dim3(C), 256, 0, stream>>>(content + fo, mu, rstd);
        final_kernel<<<dim3(N / 32, C / 32), 256, 0, stream>>>(
            content + fo, meanw, stdw, mu, rstd, out + fo);
    }
}

// Round 5
// 1107.906 us; speedup vs baseline: 1.0935x; 1.0073x over previous
//
#include <hip/hip_runtime.h>
#include <math.h>

#define BATCH 4
#define C 512
#define N 4096   // content spatial (64*64)
#define M 4096   // style spatial (64*64)
#define MSPLIT 4

typedef __attribute__((ext_vector_type(8))) short short8;
typedef __attribute__((ext_vector_type(8))) __bf16 bf16x8;
typedef __attribute__((ext_vector_type(4))) float f32x4;
typedef __attribute__((ext_vector_type(4))) unsigned int uint4v;

static __device__ __forceinline__ unsigned short f2bf(float x) {
    unsigned u = __float_as_uint(x);
    u += 0x7fff + ((u >> 16) & 1);          // round-to-nearest-even
    return (unsigned short)(u >> 16);
}
static __device__ __forceinline__ float bf2f(unsigned short h) {
    return __uint_as_float(((unsigned)h) << 16);
}
static __device__ __forceinline__ f32x4 mfma_bf16(short8 a, short8 b, f32x4 c) {
    return __builtin_amdgcn_mfma_f32_16x16x32_bf16(
        __builtin_bit_cast(bf16x8, a), __builtin_bit_cast(bf16x8, b), c, 0, 0, 0);
}
// direct global->LDS DMA, 16B per lane; lds dest must be wave-uniform base
static __device__ __forceinline__ void gload16(const void* g, void* l) {
    __builtin_amdgcn_global_load_lds(
        (const __attribute__((address_space(1))) void*)g,
        (__attribute__((address_space(3))) void*)l, 16, 0, 0);
}
// packed f32->bf16 (RTNE), 2 elems/op
static __device__ __forceinline__ unsigned cvt_pk_bf16(float a, float b) {
    unsigned r;
    asm("v_cvt_pk_bf16_f32 %0, %1, %2" : "=v"(r) : "v"(a), "v"(b));
    return r;
}

// ---------------------------------------------------------------------------
// K0: split W (512x512 fp32) into bf16 hi/lo, once per call
// ---------------------------------------------------------------------------
__global__ __launch_bounds__(256) void wsplit_kernel(
    const float* __restrict__ W, unsigned short* __restrict__ hi,
    unsigned short* __restrict__ lo)
{
    int i = blockIdx.x * 256 + threadIdx.x;
    float v = W[i];
    unsigned short h = f2bf(v);
    hi[i] = h;
    lo[i] = f2bf(v - bf2f(h));
}

// ---------------------------------------------------------------------------
// K1a: MFMA linear for Fq/Gt: out[n][o] (hi/lo bf16), o fastest.
// block 64n x 64o, BK=32, waves 2x2 (wave tile 32n x 32o)
// ---------------------------------------------------------------------------
__global__ __launch_bounds__(256) void linear_fg_mfma(
    const float* __restrict__ in,                     // [C][N] batch slice
    const unsigned short* __restrict__ Whi, const unsigned short* __restrict__ Wlo,
    const float* __restrict__ bias,
    unsigned short* __restrict__ out_hi, unsigned short* __restrict__ out_lo)
{
    __shared__ float in_s[32][68];                    // [k][n] fp32
    __shared__ __align__(16) unsigned short wh_s[64][40];  // [o][k]
    __shared__ __align__(16) unsigned short wl_s[64][40];
    const int tid = threadIdx.x;
    const int n0 = blockIdx.x * 64, o0 = blockIdx.y * 64;
    const int w = tid >> 6, lane = tid & 63;
    const int wrow = w >> 1, wcol = w & 1;
    const int lr = lane & 15, q = lane >> 4;
    f32x4 acc[2][2];
    #pragma unroll
    for (int i = 0; i < 2; ++i)
        #pragma unroll
        for (int j = 0; j < 2; ++j) acc[i][j] = (f32x4){0.f, 0.f, 0.f, 0.f};

    for (int kc = 0; kc < C; kc += 32) {
        __syncthreads();
        #pragma unroll
        for (int it = 0; it < 2; ++it) {
            int idx = tid + it * 256;
            int k = idx >> 4, seg = idx & 15;
            *(float4*)&in_s[k][seg * 4] =
                *(const float4*)&in[(size_t)(kc + k) * N + n0 + seg * 4];
        }
        {
            int o = tid >> 2, sg = tid & 3;
            *(float4*)&wh_s[o][sg * 8] = *(const float4*)&Whi[(size_t)(o0 + o) * 512 + kc + sg * 8];
            *(float4*)&wl_s[o][sg * 8] = *(const float4*)&Wlo[(size_t)(o0 + o) * 512 + kc + sg * 8];
        }
        __syncthreads();
        short8 ah[2], al[2], bh[2], bl[2];
        #pragma unroll
        for (int i = 0; i < 2; ++i) {
            int n = wrow * 32 + i * 16 + lr;
            #pragma unroll
            for (int j = 0; j < 8; ++j) {
                float f = in_s[q * 8 + j][n];
                unsigned short h = f2bf(f);
                ah[i][j] = (short)h;
                al[i][j] = (short)f2bf(f - bf2f(h));
            }
        }
        #pragma unroll
        for (int j = 0; j < 2; ++j) {
            int o = wcol * 32 + j * 16 + lr;
            bh[j] = *(const short8*)&wh_s[o][q * 8];
            bl[j] = *(const short8*)&wl_s[o][q * 8];
        }
        #pragma unroll
        for (int i = 0; i < 2; ++i)
            #pragma unroll
            for (int j = 0; j < 2; ++j) {
                acc[i][j] = mfma_bf16(ah[i], bh[j], acc[i][j]);
                acc[i][j] = mfma_bf16(ah[i], bl[j], acc[i][j]);
                acc[i][j] = mfma_bf16(al[i], bh[j], acc[i][j]);
            }
    }
    #pragma unroll
    for (int i = 0; i < 2; ++i)
        #pragma unroll
        for (int j = 0; j < 2; ++j) {
            int o = o0 + wcol * 32 + j * 16 + lr;
            float bo = bias[o];
            #pragma unroll
            for (int r = 0; r < 4; ++r) {
                int n = n0 + wrow * 32 + i * 16 + q * 4 + r;
                float v = acc[i][j][r] + bo;
                unsigned short h = f2bf(v);
                out_hi[(size_t)n * 512 + o] = h;
                out_lo[(size_t)n * 512 + o] = f2bf(v - bf2f(h));
            }
        }
}

// ---------------------------------------------------------------------------
// K1b: MFMA linear for V: vhT[o][m] only (r1-proven: apply squares in-reg)
// ---------------------------------------------------------------------------
__global__ __launch_bounds__(256) void linear_v_mfma(
    const float* __restrict__ in,                     // [C][M] batch slice
    const unsigned short* __restrict__ Whi, const unsigned short* __restrict__ Wlo,
    const float* __restrict__ bias,
    unsigned short* __restrict__ vhT)
{
    __shared__ float in_s[32][68];                    // [k][m]
    __shared__ __align__(16) unsigned short wh_s[64][40];
    __shared__ __align__(16) unsigned short wl_s[64][40];
    const int tid = threadIdx.x;
    const int m0 = blockIdx.x * 64, o0 = blockIdx.y * 64;
    const int w = tid >> 6, lane = tid & 63;
    const int wrow = w >> 1, wcol = w & 1;
    const int lr = lane & 15, q = lane >> 4;
    f32x4 acc[2][2];
    #pragma unroll
    for (int i = 0; i < 2; ++i)
        #pragma unroll
        for (int j = 0; j < 2; ++j) acc[i][j] = (f32x4){0.f, 0.f, 0.f, 0.f};

    for (int kc = 0; kc < C; kc += 32) {
        __syncthreads();
        #pragma unroll
        for (int it = 0; it < 2; ++it) {
            int idx = tid + it * 256;
            int k = idx >> 4, seg = idx & 15;
            *(float4*)&in_s[k][seg * 4] =
                *(const float4*)&in[(size_t)(kc + k) * N + m0 + seg * 4];
        }
        {
            int o = tid >> 2, sg = tid & 3;
            *(float4*)&wh_s[o][sg * 8] = *(const float4*)&Whi[(size_t)(o0 + o) * 512 + kc + sg * 8];
            *(float4*)&wl_s[o][sg * 8] = *(const float4*)&Wlo[(size_t)(o0 + o) * 512 + kc + sg * 8];
        }
        __syncthreads();
        short8 ah[2], al[2], bh[2], bl[2];
        #pragma unroll
        for (int i = 0; i < 2; ++i) {
            int o = wrow * 32 + i * 16 + lr;
            ah[i] = *(const short8*)&wh_s[o][q * 8];
            al[i] = *(const short8*)&wl_s[o][q * 8];
        }
        #pragma unroll
        for (int j = 0; j < 2; ++j) {
            int m = wcol * 32 + j * 16 + lr;
            #pragma unroll
            for (int t = 0; t < 8; ++t) {
                float f = in_s[q * 8 + t][m];
                unsigned short h = f2bf(f);
                bh[j][t] = (short)h;
                bl[j][t] = (short)f2bf(f - bf2f(h));
            }
        }
        #pragma unroll
        for (int i = 0; i < 2; ++i)
            #pragma unroll
            for (int j = 0; j < 2; ++j) {
                acc[i][j] = mfma_bf16(ah[i], bh[j], acc[i][j]);
                acc[i][j] = mfma_bf16(ah[i], bl[j], acc[i][j]);
                acc[i][j] = mfma_bf16(al[i], bh[j], acc[i][j]);
            }
    }
    #pragma unroll
    for (int i = 0; i < 2; ++i)
        #pragma unroll
        for (int r = 0; r < 4; ++r) {
            int o = o0 + wrow * 32 + i * 16 + q * 4 + r;
            float bo = bias[o];
            #pragma unroll
            for (int j = 0; j < 2; ++j) {
                int m = m0 + wcol * 32 + j * 16 + lr;
                float v = acc[i][j][r] + bo;
                vhT[(size_t)o * M + m] = f2bf(v);
            }
        }
}

// ---------------------------------------------------------------------------
// K2: logits MFMA: S[n][m] = Ah.BhT + Ah.BlT + Al.BhT  (hi/lo bf16 split)
// block tile 128n x 128m, BK=32, 4 waves (2x2), wave tile 64x64.
// Staging via global_load_lds (16B/lane DMA), unpadded [row][32] LDS.
// Flat 1024-block grid with XCD grouping: all 32 m-tiles of 4 n-rows land
// on one XCD consecutively -> A panels (Ah/Al rows) are L2-hot.
// ---------------------------------------------------------------------------
__global__ __launch_bounds__(256) void logits_mfma_kernel(
    const unsigned short* __restrict__ Ah, const unsigned short* __restrict__ Al,
    const unsigned short* __restrict__ Bh, const unsigned short* __restrict__ Bl,
    float* __restrict__ S)
{
    __shared__ __align__(16) unsigned short Ah_s[128 * 32];
    __shared__ __align__(16) unsigned short Al_s[128 * 32];
    __shared__ __align__(16) unsigned short Bh_s[128 * 32];
    __shared__ __align__(16) unsigned short Bl_s[128 * 32];
    const int tid = threadIdx.x;
    // XCD-grouped decode: bid%8 = XCD (round-robin dispatch). XCD x handles
    // n-tiles {4x..4x+3}; within-XCD index j: m fastest (32), then n (4).
    const int bid = blockIdx.x;
    const int xcd = bid & 7, j = bid >> 3;            // j: 0..127
    const int m0 = (j & 31) * 128;
    const int n0 = (xcd * 4 + (j >> 5)) * 128;
    const int w = tid >> 6, lane = tid & 63;
    const int wrow = w >> 1, wcol = w & 1;
    const int lr = lane & 15, q = lane >> 4;
    const int srow = lane >> 2, scol = (lane & 3) * 8;   // staging: 16 rows x 64B per instr
    f32x4 acc[4][4];
    #pragma unroll
    for (int i = 0; i < 4; ++i)
        #pragma unroll
        for (int j2 = 0; j2 < 4; ++j2)
            acc[i][j2] = (f32x4){0.f, 0.f, 0.f, 0.f};

    for (int kc = 0; kc < C; kc += 32) {
        __syncthreads();
        #pragma unroll
        for (int g2 = 0; g2 < 2; ++g2) {
            int g = w * 2 + g2;                          // chunk 0..7 (16 rows each)
            size_t ga = (size_t)(n0 + g * 16 + srow) * C + kc + scol;
            size_t gb = (size_t)(m0 + g * 16 + srow) * C + kc + scol;
            int lo = g * 512;                            // 16 rows * 32 shorts
            gload16(&Ah[ga], &Ah_s[lo]);
            gload16(&Al[ga], &Al_s[lo]);
            gload16(&Bh[gb], &Bh_s[lo]);
            gload16(&Bl[gb], &Bl_s[lo]);
        }
        __syncthreads();
        short8 ah[4], al[4], bh[4], bl[4];
        #pragma unroll
        for (int i = 0; i < 4; ++i) {
            int ro = (wrow * 64 + i * 16 + lr) * 32 + q * 8;
            int co = (wcol * 64 + i * 16 + lr) * 32 + q * 8;
            ah[i] = *(const short8*)&Ah_s[ro];
            al[i] = *(const short8*)&Al_s[ro];
            bh[i] = *(const short8*)&Bh_s[co];
            bl[i] = *(const short8*)&Bl_s[co];
        }
        #pragma unroll
        for (int i = 0; i < 4; ++i)
            #pragma unroll
            for (int j2 = 0; j2 < 4; ++j2) {
                acc[i][j2] = mfma_bf16(ah[i], bh[j2], acc[i][j2]);
                acc[i][j2] = mfma_bf16(ah[i], bl[j2], acc[i][j2]);
                acc[i][j2] = mfma_bf16(al[i], bh[j2], acc[i][j2]);
            }
    }
    #pragma unroll
    for (int i = 0; i < 4; ++i) {
        int nb = n0 + wrow * 64 + i * 16 + q * 4;
        #pragma unroll
        for (int j2 = 0; j2 < 4; ++j2) {
            int m = m0 + wcol * 64 + j2 * 16 + lr;
            #pragma unroll
            for (int r = 0; r < 4; ++r)
                S[(size_t)(nb + r) * M + m] = acc[i][j2][r];
        }
    }
}

// ---------------------------------------------------------------------------
// K3: row softmax -> bf16 P, rsum = sum of the ROUNDED p (consistency!)
// ---------------------------------------------------------------------------
__global__ __launch_bounds__(256) void rowstat_p_kernel(
    const float* __restrict__ S, unsigned short* __restrict__ P,
    float* __restrict__ rsum)
{
    const int n = blockIdx.x;
    const int tid = threadIdx.x;
    const float* row = S + (size_t)n * M;
    float v[16];
    #pragma unroll
    for (int i = 0; i < 16; ++i) v[i] = row[tid + i * 256];
    float lm = -INFINITY;
    #pragma unroll
    for (int i = 0; i < 16; ++i) lm = fmaxf(lm, v[i]);
    #pragma unroll
    for (int off = 32; off > 0; off >>= 1) lm = fmaxf(lm, __shfl_xor(lm, off, 64));
    __shared__ float red[4];
    __shared__ float redsum[4];
    const int wid = tid >> 6, lane = tid & 63;
    if (lane == 0) red[wid] = lm;
    __syncthreads();
    const float rm = fmaxf(fmaxf(red[0], red[1]), fmaxf(red[2], red[3]));
    float ls = 0.f;
    unsigned short* prow = P + (size_t)n * M;
    #pragma unroll
    for (int i = 0; i < 16; ++i) {
        float p = __expf(v[i] - rm);
        unsigned short pb = f2bf(p);
        prow[tid + i * 256] = pb;
        ls += bf2f(pb);
    }
    #pragma unroll
    for (int off = 32; off > 0; off >>= 1) ls += __shfl_xor(ls, off, 64);
    if (lane == 0) redsum[wid] = ls;
    __syncthreads();
    if (tid == 0) rsum[n] = redsum[0] + redsum[1] + redsum[2] + redsum[3];
}

// ---------------------------------------------------------------------------
// K4: apply partial (split-M) — r1-proven dataflow (P + VhT streams, in-reg
// V^2 hi/lo, serial DMA staging) + XCD-GROUPED flat grid:
//   bid%8 = XCD; all 8 c-blocks of one (n0,z) group run consecutively on
//   the SAME XCD -> P panel (256KB) fetched once per group, L2-hot for the
//   other 7 blocks. Groups ordered z-major so the 1MB Vh z-panel stays
//   L2-resident across 4 consecutive n-groups.
// ---------------------------------------------------------------------------
__global__ __launch_bounds__(256) void apply_partial_kernel(
    const unsigned short* __restrict__ P, const unsigned short* __restrict__ VhT,
    float* __restrict__ accm_p, float* __restrict__ acc2_p)
{
    __shared__ __align__(16) unsigned short P_s[128 * 32];
    __shared__ __align__(16) unsigned short Vh_s[64 * 32];
    const int tid = threadIdx.x;
    // decode: bid = (group-local j)*8 + xcd; j = glocal*8 + cblk
    const int bid = blockIdx.x;
    const int xcd = bid & 7, j = bid >> 3;            // j: 0..127
    const int c0 = (j & 7) * 64;                      // 8 c-blocks per group
    const int gl = j >> 3;                            // group-local: 0..15
    const int z  = gl >> 2;                           // 4 consecutive groups share z
    const int n0 = (xcd * 4 + (gl & 3)) * 128;        // XCD owns n-rows 4x..4x+3
    const int w = tid >> 6, lane = tid & 63;
    const int wrow = w >> 1, wcol = w & 1;
    const int lr = lane & 15, q = lane >> 4;
    const int srow = lane >> 2, scol = (lane & 3) * 8;
    f32x4 accm[4][2], acc2[4][2];
    #pragma unroll
    for (int i = 0; i < 4; ++i)
        #pragma unroll
        for (int j2 = 0; j2 < 2; ++j2) {
            accm[i][j2] = (f32x4){0.f, 0.f, 0.f, 0.f};
            acc2[i][j2] = (f32x4){0.f, 0.f, 0.f, 0.f};
        }

    const int mbeg = z * (M / MSPLIT);
    for (int mc = mbeg; mc < mbeg + M / MSPLIT; mc += 32) {
        __syncthreads();
        #pragma unroll
        for (int g2 = 0; g2 < 2; ++g2) {
            int g = w * 2 + g2;                          // P chunk 0..7
            gload16(&P[(size_t)(n0 + g * 16 + srow) * M + mc + scol], &P_s[g * 512]);
        }
        gload16(&VhT[(size_t)(c0 + w * 16 + srow) * M + mc + scol], &Vh_s[w * 512]);
        __syncthreads();
        short8 a[4], bh[2], b2h[2], b2l[2];
        #pragma unroll
        for (int i = 0; i < 4; ++i)
            a[i] = *(const short8*)&P_s[(wrow * 64 + i * 16 + lr) * 32 + q * 8];
        #pragma unroll
        for (int j2 = 0; j2 < 2; ++j2) {
            bh[j2] = *(const short8*)&Vh_s[(wcol * 32 + j2 * 16 + lr) * 32 + q * 8];
            uint4v u = __builtin_bit_cast(uint4v, bh[j2]);
            uint4v hv, lv;
            #pragma unroll
            for (int t = 0; t < 4; ++t) {
                float v0 = __uint_as_float(u[t] << 16);
                float v1 = __uint_as_float(u[t] & 0xffff0000u);
                float s0 = v0 * v0, s1 = v1 * v1;
                unsigned hh = cvt_pk_bf16(s0, s1);
                float r0 = s0 - __uint_as_float(hh << 16);
                float r1 = s1 - __uint_as_float(hh & 0xffff0000u);
                hv[t] = hh;
                lv[t] = cvt_pk_bf16(r0, r1);
            }
            b2h[j2] = __builtin_bit_cast(short8, hv);
            b2l[j2] = __builtin_bit_cast(short8, lv);
        }
        #pragma unroll
        for (int i = 0; i < 4; ++i)
            #pragma unroll
            for (int j2 = 0; j2 < 2; ++j2) {
                accm[i][j2] = mfma_bf16(a[i], bh[j2],  accm[i][j2]);
                acc2[i][j2] = mfma_bf16(a[i], b2h[j2], acc2[i][j2]);
                acc2[i][j2] = mfma_bf16(a[i], b2l[j2], acc2[i][j2]);
            }
    }
    const size_t pbase = (size_t)z * N * C;
    #pragma unroll
    for (int i = 0; i < 4; ++i) {
        int nb = n0 + wrow * 64 + i * 16 + q * 4;
        #pragma unroll
        for (int j2 = 0; j2 < 2; ++j2) {
            int c = c0 + wcol * 32 + j2 * 16 + lr;
            #pragma unroll
            for (int r = 0; r < 4; ++r) {
                size_t off = pbase + (size_t)(nb + r) * C + c;
                accm_p[off] = accm[i][j2][r];
                acc2_p[off] = acc2[i][j2][r];
            }
        }
    }
}

// ---------------------------------------------------------------------------
// K4b: combine partials -> mean/std (fp32). One float4 of c per thread.
// ---------------------------------------------------------------------------
__global__ __launch_bounds__(256) void combine_kernel(
    const float* __restrict__ accm_p, const float* __restrict__ acc2_p,
    const float* __restrict__ rsum, float* __restrict__ meanw,
    float* __restrict__ stdw)
{
    const size_t idx = ((size_t)blockIdx.x * 256 + threadIdx.x) * 4;
    const int n = (int)(idx >> 9);        // /C (C=512)
    const float inv = 1.0f / rsum[n];
    float sm[4] = {0.f, 0.f, 0.f, 0.f}, s2[4] = {0.f, 0.f, 0.f, 0.f};
    #pragma unroll
    for (int z = 0; z < MSPLIT; ++z) {
        float4 a = *(const float4*)&accm_p[(size_t)z * N * C + idx];
        float4 b = *(const float4*)&acc2_p[(size_t)z * N * C + idx];
        sm[0] += a.x; sm[1] += a.y; sm[2] += a.z; sm[3] += a.w;
        s2[0] += b.x; s2[1] += b.y; s2[2] += b.z; s2[3] += b.w;
    }
    float4 mnv, sdv;
    float* mp = (float*)&mnv;
    float* sp = (float*)&sdv;
    #pragma unroll
    for (int k = 0; k < 4; ++k) {
        float mn = sm[k] * inv;
        float m2 = s2[k] * inv;
        mp[k] = mn;
        sp[k] = sqrtf(fmaxf(m2 - mn * mn, 0.f));
    }
    *(float4*)&meanw[idx] = mnv;
    *(float4*)&stdw[idx]  = sdv;
}

// ---------------------------------------------------------------------------
// K5: instance-norm stats per channel (fp32)
// ---------------------------------------------------------------------------
__global__ __launch_bounds__(256) void mvn_kernel(
    const float* __restrict__ content, float* __restrict__ mu, float* __restrict__ rstd)
{
    const int c = blockIdx.x;
    const int tid = threadIdx.x;
    const float* row = content + (size_t)c * N;
    float s = 0.f, ss = 0.f;
    for (int i = tid; i < N; i += 256) {
        float v = row[i];
        s += v;
        ss = fmaf(v, v, ss);
    }
    #pragma unroll
    for (int off = 32; off > 0; off >>= 1) {
        s  += __shfl_xor(s,  off, 64);
        ss += __shfl_xor(ss, off, 64);
    }
    __shared__ float rs[4], rss[4];
    const int wid = tid >> 6, lane = tid & 63;
    if (lane == 0) { rs[wid] = s; rss[wid] = ss; }
    __syncthreads();
    if (tid == 0) {
        float st = rs[0] + rs[1] + rs[2] + rs[3];
        float sst = rss[0] + rss[1] + rss[2] + rss[3];
        float m = st / (float)N;
        float var = (sst - st * st / (float)N) / (float)(N - 1);
        mu[c] = m;
        rstd[c] = rsqrtf(var + 1e-5f);
    }
}

// ---------------------------------------------------------------------------
// K6: final combine (fp32)
// ---------------------------------------------------------------------------
__global__ __launch_bounds__(256) void final_kernel(
    const float* __restrict__ content, const float* __restrict__ meanw,
    const float* __restrict__ stdw, const float* __restrict__ mu,
    const float* __restrict__ rstd, float* __restrict__ out)
{
    __shared__ float mn_s[32][33], sd_s[32][33];
    const int tid = threadIdx.x;
    const int n0 = blockIdx.x * 32;
    const int c0 = blockIdx.y * 32;
    const int tx = tid & 31, ty = tid >> 5;
    #pragma unroll
    for (int i = 0; i < 4; ++i) {
        int n = ty + i * 8;
        mn_s[tx][n] = meanw[(size_t)(n0 + n) * C + c0 + tx];
        sd_s[tx][n] = stdw [(size_t)(n0 + n) * C + c0 + tx];
    }
    __syncthreads();
    #pragma unroll
    for (int i = 0; i < 4; ++i) {
        int c = ty + i * 8;
        float m = mu[c0 + c], r = rstd[c0 + c];
        size_t off = (size_t)(c0 + c) * N + n0 + tx;
        float x = content[off];
        out[off] = sd_s[c][tx] * (x - m) * r + mn_s[c][tx];
    }
}

// ---------------------------------------------------------------------------
extern "C" void kernel_launch(void* const* d_in, const int* in_sizes, int n_in,
                              void* d_out, int out_size, void* d_ws, size_t ws_size,
                              hipStream_t stream)
{
    const float* content = (const float*)d_in[0];
    const float* style   = (const float*)d_in[1];
    const float* ckey    = (const float*)d_in[2];
    const float* skey    = (const float*)d_in[3];
    const float* Wf      = (const float*)d_in[4];
    const float* bf      = (const float*)d_in[5];
    const float* Wg      = (const float*)d_in[6];
    const float* bg      = (const float*)d_in[7];
    const float* Wh      = (const float*)d_in[8];
    const float* bh      = (const float*)d_in[9];
    float* out = (float*)d_out;

    const size_t sz_w  = (size_t)512 * 512 * 2;      // one W half
    const size_t sz_S  = (size_t)N * M * 4;          // 64 MB (aliased by partials)
    const size_t sz_FG = (size_t)N * C * 2;
    const size_t sz_P  = (size_t)N * M * 2;
    const size_t sz_V  = (size_t)C * M * 2;

    char* p = (char*)d_ws;
    auto alloc = [&](size_t bytes) {
        char* r = p;
        p += (bytes + 255) & ~(size_t)255;
        return r;
    };
    unsigned short* WfH = (unsigned short*)alloc(sz_w);
    unsigned short* WfL = (unsigned short*)alloc(sz_w);
    unsigned short* WgH = (unsigned short*)alloc(sz_w);
    unsigned short* WgL = (unsigned short*)alloc(sz_w);
    unsigned short* WhH = (unsigned short*)alloc(sz_w);
    unsigned short* WhL = (unsigned short*)alloc(sz_w);
    float* S = (float*)alloc(sz_S);                  // also: partial accm/acc2
    unsigned short* Fh = (unsigned short*)alloc(sz_FG);
    unsigned short* Fl = (unsigned short*)alloc(sz_FG);
    unsigned short* Gh = (unsigned short*)alloc(sz_FG);
    unsigned short* Gl = (unsigned short*)alloc(sz_FG);
    unsigned short* P    = (unsigned short*)alloc(sz_P);
    unsigned short* VhT  = (unsigned short*)alloc(sz_V);
    float* rsum  = (float*)alloc((size_t)N * 4);
    float* meanw = (float*)alloc((size_t)N * C * 4);
    float* stdw  = (float*)alloc((size_t)N * C * 4);
    float* mu    = (float*)alloc((size_t)C * 4);
    float* rstd  = (float*)alloc((size_t)C * 4);

    // partials alias S (dead between rowstat and next batch's logits):
    // accm_p = MSPLIT*N*C floats, acc2_p = MSPLIT*N*C floats = exactly N*M
    float* accm_p = S;
    float* acc2_p = S + (size_t)MSPLIT * N * C;

    wsplit_kernel<<<dim3(1024), 256, 0, stream>>>(Wf, WfH, WfL);
    wsplit_kernel<<<dim3(1024), 256, 0, stream>>>(Wg, WgH, WgL);
    wsplit_kernel<<<dim3(1024), 256, 0, stream>>>(Wh, WhH, WhL);

    for (int b = 0; b < BATCH; ++b) {
        const size_t fo = (size_t)b * C * N;
        linear_fg_mfma<<<dim3(N / 64, C / 64), 256, 0, stream>>>(ckey + fo, WfH, WfL, bf, Fh, Fl);
        linear_fg_mfma<<<dim3(M / 64, C / 64), 256, 0, stream>>>(skey + fo, WgH, WgL, bg, Gh, Gl);
        linear_v_mfma<<<dim3(M / 64, C / 64), 256, 0, stream>>>(style + fo, WhH, WhL, bh, VhT);
        logits_mfma_kernel<<<dim3(1024), 256, 0, stream>>>(Fh, Fl, Gh, Gl, S);
        rowstat_p_kernel<<<dim3(N), 256, 0, stream>>>(S, P, rsum);
        apply_partial_kernel<<<dim3(1024), 256, 0, stream>>>(
            P, VhT, accm_p, acc2_p);
        combine_kernel<<<dim3(N * C / 1024), 256, 0, stream>>>(
            accm_p, acc2_p, rsum, meanw, stdw);
        mvn_kernel<<<dim3(C), 256, 0, stream>>>(content + fo, mu, rstd);
        final_kernel<<<dim3(N / 32, C / 32), 256, 0, stream>>>(
            content + fo, meanw, stdw, mu, rstd, out + fo);
    }
}

// Round 6
// 1085.740 us; speedup vs baseline: 1.1158x; 1.0204x over previous
//
#include <hip/hip_runtime.h>
#include <math.h>

#define BATCH 4
#define C 512
#define N 4096   // content spatial (64*64)
#define M 4096   // style spatial (64*64)
#define MSPLIT 4

typedef __attribute__((ext_vector_type(8))) short short8;
typedef __attribute__((ext_vector_type(8))) __bf16 bf16x8;
typedef __attribute__((ext_vector_type(4))) float f32x4;

static __device__ __forceinline__ unsigned short f2bf(float x) {
    unsigned u = __float_as_uint(x);
    u += 0x7fff + ((u >> 16) & 1);          // round-to-nearest-even
    return (unsigned short)(u >> 16);
}
static __device__ __forceinline__ float bf2f(unsigned short h) {
    return __uint_as_float(((unsigned)h) << 16);
}
static __device__ __forceinline__ f32x4 mfma_bf16(short8 a, short8 b, f32x4 c) {
    return __builtin_amdgcn_mfma_f32_16x16x32_bf16(
        __builtin_bit_cast(bf16x8, a), __builtin_bit_cast(bf16x8, b), c, 0, 0, 0);
}
// direct global->LDS DMA, 16B per lane; lds dest must be wave-uniform base
static __device__ __forceinline__ void gload16(const void* g, void* l) {
    __builtin_amdgcn_global_load_lds(
        (const __attribute__((address_space(1))) void*)g,
        (__attribute__((address_space(3))) void*)l, 16, 0, 0);
}

// ---------------------------------------------------------------------------
// K0: split W (512x512 fp32) into bf16 hi/lo, once per call
// ---------------------------------------------------------------------------
__global__ __launch_bounds__(256) void wsplit_kernel(
    const float* __restrict__ W, unsigned short* __restrict__ hi,
    unsigned short* __restrict__ lo)
{
    int i = blockIdx.x * 256 + threadIdx.x;
    float v = W[i];
    unsigned short h = f2bf(v);
    hi[i] = h;
    lo[i] = f2bf(v - bf2f(h));
}

// ---------------------------------------------------------------------------
// K1a: MFMA linear for Fq/Gt: out[n][o] (hi/lo bf16), o fastest.
// block 64n x 64o, BK=32, waves 2x2 (wave tile 32n x 32o)
// ---------------------------------------------------------------------------
__global__ __launch_bounds__(256) void linear_fg_mfma(
    const float* __restrict__ in,                     // [C][N] batch slice
    const unsigned short* __restrict__ Whi, const unsigned short* __restrict__ Wlo,
    const float* __restrict__ bias,
    unsigned short* __restrict__ out_hi, unsigned short* __restrict__ out_lo)
{
    __shared__ float in_s[32][68];                    // [k][n] fp32
    __shared__ __align__(16) unsigned short wh_s[64][40];  // [o][k]
    __shared__ __align__(16) unsigned short wl_s[64][40];
    const int tid = threadIdx.x;
    const int n0 = blockIdx.x * 64, o0 = blockIdx.y * 64;
    const int w = tid >> 6, lane = tid & 63;
    const int wrow = w >> 1, wcol = w & 1;
    const int lr = lane & 15, q = lane >> 4;
    f32x4 acc[2][2];
    #pragma unroll
    for (int i = 0; i < 2; ++i)
        #pragma unroll
        for (int j = 0; j < 2; ++j) acc[i][j] = (f32x4){0.f, 0.f, 0.f, 0.f};

    for (int kc = 0; kc < C; kc += 32) {
        __syncthreads();
        #pragma unroll
        for (int it = 0; it < 2; ++it) {
            int idx = tid + it * 256;
            int k = idx >> 4, seg = idx & 15;
            *(float4*)&in_s[k][seg * 4] =
                *(const float4*)&in[(size_t)(kc + k) * N + n0 + seg * 4];
        }
        {
            int o = tid >> 2, sg = tid & 3;
            *(float4*)&wh_s[o][sg * 8] = *(const float4*)&Whi[(size_t)(o0 + o) * 512 + kc + sg * 8];
            *(float4*)&wl_s[o][sg * 8] = *(const float4*)&Wlo[(size_t)(o0 + o) * 512 + kc + sg * 8];
        }
        __syncthreads();
        short8 ah[2], al[2], bh[2], bl[2];
        #pragma unroll
        for (int i = 0; i < 2; ++i) {
            int n = wrow * 32 + i * 16 + lr;
            #pragma unroll
            for (int j = 0; j < 8; ++j) {
                float f = in_s[q * 8 + j][n];
                unsigned short h = f2bf(f);
                ah[i][j] = (short)h;
                al[i][j] = (short)f2bf(f - bf2f(h));
            }
        }
        #pragma unroll
        for (int j = 0; j < 2; ++j) {
            int o = wcol * 32 + j * 16 + lr;
            bh[j] = *(const short8*)&wh_s[o][q * 8];
            bl[j] = *(const short8*)&wl_s[o][q * 8];
        }
        #pragma unroll
        for (int i = 0; i < 2; ++i)
            #pragma unroll
            for (int j = 0; j < 2; ++j) {
                acc[i][j] = mfma_bf16(ah[i], bh[j], acc[i][j]);
                acc[i][j] = mfma_bf16(ah[i], bl[j], acc[i][j]);
                acc[i][j] = mfma_bf16(al[i], bh[j], acc[i][j]);
            }
    }
    #pragma unroll
    for (int i = 0; i < 2; ++i)
        #pragma unroll
        for (int j = 0; j < 2; ++j) {
            int o = o0 + wcol * 32 + j * 16 + lr;
            float bo = bias[o];
            #pragma unroll
            for (int r = 0; r < 4; ++r) {
                int n = n0 + wrow * 32 + i * 16 + q * 4 + r;
                float v = acc[i][j][r] + bo;
                unsigned short h = f2bf(v);
                out_hi[(size_t)n * 512 + o] = h;
                out_lo[(size_t)n * 512 + o] = f2bf(v - bf2f(h));
            }
        }
}

// ---------------------------------------------------------------------------
// K1b: MFMA linear for V: vhT[o][m] + precomputed v2hT/v2lT = hi/lo of vh^2
// (producer-side squaring: removes the VALU wall in apply; bit-identical
// to the in-register path since both start from the rounded vh).
// ---------------------------------------------------------------------------
__global__ __launch_bounds__(256) void linear_v_mfma(
    const float* __restrict__ in,                     // [C][M] batch slice
    const unsigned short* __restrict__ Whi, const unsigned short* __restrict__ Wlo,
    const float* __restrict__ bias,
    unsigned short* __restrict__ vhT, unsigned short* __restrict__ v2hT,
    unsigned short* __restrict__ v2lT)
{
    __shared__ float in_s[32][68];                    // [k][m]
    __shared__ __align__(16) unsigned short wh_s[64][40];
    __shared__ __align__(16) unsigned short wl_s[64][40];
    const int tid = threadIdx.x;
    const int m0 = blockIdx.x * 64, o0 = blockIdx.y * 64;
    const int w = tid >> 6, lane = tid & 63;
    const int wrow = w >> 1, wcol = w & 1;
    const int lr = lane & 15, q = lane >> 4;
    f32x4 acc[2][2];
    #pragma unroll
    for (int i = 0; i < 2; ++i)
        #pragma unroll
        for (int j = 0; j < 2; ++j) acc[i][j] = (f32x4){0.f, 0.f, 0.f, 0.f};

    for (int kc = 0; kc < C; kc += 32) {
        __syncthreads();
        #pragma unroll
        for (int it = 0; it < 2; ++it) {
            int idx = tid + it * 256;
            int k = idx >> 4, seg = idx & 15;
            *(float4*)&in_s[k][seg * 4] =
                *(const float4*)&in[(size_t)(kc + k) * N + m0 + seg * 4];
        }
        {
            int o = tid >> 2, sg = tid & 3;
            *(float4*)&wh_s[o][sg * 8] = *(const float4*)&Whi[(size_t)(o0 + o) * 512 + kc + sg * 8];
            *(float4*)&wl_s[o][sg * 8] = *(const float4*)&Wlo[(size_t)(o0 + o) * 512 + kc + sg * 8];
        }
        __syncthreads();
        short8 ah[2], al[2], bh[2], bl[2];
        #pragma unroll
        for (int i = 0; i < 2; ++i) {
            int o = wrow * 32 + i * 16 + lr;
            ah[i] = *(const short8*)&wh_s[o][q * 8];
            al[i] = *(const short8*)&wl_s[o][q * 8];
        }
        #pragma unroll
        for (int j = 0; j < 2; ++j) {
            int m = wcol * 32 + j * 16 + lr;
            #pragma unroll
            for (int t = 0; t < 8; ++t) {
                float f = in_s[q * 8 + t][m];
                unsigned short h = f2bf(f);
                bh[j][t] = (short)h;
                bl[j][t] = (short)f2bf(f - bf2f(h));
            }
        }
        #pragma unroll
        for (int i = 0; i < 2; ++i)
            #pragma unroll
            for (int j = 0; j < 2; ++j) {
                acc[i][j] = mfma_bf16(ah[i], bh[j], acc[i][j]);
                acc[i][j] = mfma_bf16(ah[i], bl[j], acc[i][j]);
                acc[i][j] = mfma_bf16(al[i], bh[j], acc[i][j]);
            }
    }
    #pragma unroll
    for (int i = 0; i < 2; ++i)
        #pragma unroll
        for (int r = 0; r < 4; ++r) {
            int o = o0 + wrow * 32 + i * 16 + q * 4 + r;
            float bo = bias[o];
            #pragma unroll
            for (int j = 0; j < 2; ++j) {
                int m = m0 + wcol * 32 + j * 16 + lr;
                float v = acc[i][j][r] + bo;
                unsigned short vh = f2bf(v);
                float vhf = bf2f(vh);
                float vsq = vhf * vhf;
                unsigned short v2h = f2bf(vsq);
                unsigned short v2l = f2bf(vsq - bf2f(v2h));
                size_t off = (size_t)o * M + m;
                vhT[off] = vh;
                v2hT[off] = v2h;
                v2lT[off] = v2l;
            }
        }
}

// ---------------------------------------------------------------------------
// K2: logits MFMA: S[n][m] = Ah.BhT + Ah.BlT + Al.BhT  (hi/lo bf16 split)
// block tile 128n x 128m, BK=32, 4 waves (2x2), wave tile 64x64.
// Staging via global_load_lds (16B/lane DMA), unpadded [row][32] LDS.
// r1 grid (2D, m-major linear bid): implicit XCD locality — bid%8 fixes
// m-tile%8 per XCD, so each XCD's B panel is 1MB and L2-hot. Don't touch.
// ---------------------------------------------------------------------------
__global__ __launch_bounds__(256) void logits_mfma_kernel(
    const unsigned short* __restrict__ Ah, const unsigned short* __restrict__ Al,
    const unsigned short* __restrict__ Bh, const unsigned short* __restrict__ Bl,
    float* __restrict__ S)
{
    __shared__ __align__(16) unsigned short Ah_s[128 * 32];
    __shared__ __align__(16) unsigned short Al_s[128 * 32];
    __shared__ __align__(16) unsigned short Bh_s[128 * 32];
    __shared__ __align__(16) unsigned short Bl_s[128 * 32];
    const int tid = threadIdx.x;
    const int n0 = blockIdx.y * 128, m0 = blockIdx.x * 128;
    const int w = tid >> 6, lane = tid & 63;
    const int wrow = w >> 1, wcol = w & 1;
    const int lr = lane & 15, q = lane >> 4;
    const int srow = lane >> 2, scol = (lane & 3) * 8;   // staging: 16 rows x 64B per instr
    f32x4 acc[4][4];
    #pragma unroll
    for (int i = 0; i < 4; ++i)
        #pragma unroll
        for (int j = 0; j < 4; ++j)
            acc[i][j] = (f32x4){0.f, 0.f, 0.f, 0.f};

    for (int kc = 0; kc < C; kc += 32) {
        __syncthreads();
        #pragma unroll
        for (int g2 = 0; g2 < 2; ++g2) {
            int g = w * 2 + g2;                          // chunk 0..7 (16 rows each)
            size_t ga = (size_t)(n0 + g * 16 + srow) * C + kc + scol;
            size_t gb = (size_t)(m0 + g * 16 + srow) * C + kc + scol;
            int lo = g * 512;                            // 16 rows * 32 shorts
            gload16(&Ah[ga], &Ah_s[lo]);
            gload16(&Al[ga], &Al_s[lo]);
            gload16(&Bh[gb], &Bh_s[lo]);
            gload16(&Bl[gb], &Bl_s[lo]);
        }
        __syncthreads();
        short8 ah[4], al[4], bh[4], bl[4];
        #pragma unroll
        for (int i = 0; i < 4; ++i) {
            int ro = (wrow * 64 + i * 16 + lr) * 32 + q * 8;
            int co = (wcol * 64 + i * 16 + lr) * 32 + q * 8;
            ah[i] = *(const short8*)&Ah_s[ro];
            al[i] = *(const short8*)&Al_s[ro];
            bh[i] = *(const short8*)&Bh_s[co];
            bl[i] = *(const short8*)&Bl_s[co];
        }
        #pragma unroll
        for (int i = 0; i < 4; ++i)
            #pragma unroll
            for (int j = 0; j < 4; ++j) {
                acc[i][j] = mfma_bf16(ah[i], bh[j], acc[i][j]);
                acc[i][j] = mfma_bf16(ah[i], bl[j], acc[i][j]);
                acc[i][j] = mfma_bf16(al[i], bh[j], acc[i][j]);
            }
    }
    #pragma unroll
    for (int i = 0; i < 4; ++i) {
        int nb = n0 + wrow * 64 + i * 16 + q * 4;
        #pragma unroll
        for (int j = 0; j < 4; ++j) {
            int m = m0 + wcol * 64 + j * 16 + lr;
            #pragma unroll
            for (int r = 0; r < 4; ++r)
                S[(size_t)(nb + r) * M + m] = acc[i][j][r];
        }
    }
}

// ---------------------------------------------------------------------------
// K3: row softmax -> bf16 P, rsum = sum of the ROUNDED p (consistency!)
// ---------------------------------------------------------------------------
__global__ __launch_bounds__(256) void rowstat_p_kernel(
    const float* __restrict__ S, unsigned short* __restrict__ P,
    float* __restrict__ rsum)
{
    const int n = blockIdx.x;
    const int tid = threadIdx.x;
    const float* row = S + (size_t)n * M;
    float v[16];
    #pragma unroll
    for (int i = 0; i < 16; ++i) v[i] = row[tid + i * 256];
    float lm = -INFINITY;
    #pragma unroll
    for (int i = 0; i < 16; ++i) lm = fmaxf(lm, v[i]);
    #pragma unroll
    for (int off = 32; off > 0; off >>= 1) lm = fmaxf(lm, __shfl_xor(lm, off, 64));
    __shared__ float red[4];
    __shared__ float redsum[4];
    const int wid = tid >> 6, lane = tid & 63;
    if (lane == 0) red[wid] = lm;
    __syncthreads();
    const float rm = fmaxf(fmaxf(red[0], red[1]), fmaxf(red[2], red[3]));
    float ls = 0.f;
    unsigned short* prow = P + (size_t)n * M;
    #pragma unroll
    for (int i = 0; i < 16; ++i) {
        float p = __expf(v[i] - rm);
        unsigned short pb = f2bf(p);
        prow[tid + i * 256] = pb;
        ls += bf2f(pb);
    }
    #pragma unroll
    for (int off = 32; off > 0; off >>= 1) ls += __shfl_xor(ls, off, 64);
    if (lane == 0) redsum[wid] = ls;
    __syncthreads();
    if (tid == 0) rsum[n] = redsum[0] + redsum[1] + redsum[2] + redsum[3];
}

// ---------------------------------------------------------------------------
// K4: apply partial (split-M). 5 streams (P, Vh, V2h, V2l precomputed), all
// DMA-staged, serial stage/compute, XCD-GROUPED flat grid (r5-proven):
//   bid%8 = XCD; 8 c-blocks of one (n0,z) group run consecutively on the
//   same XCD -> P panel fetched once per group; z-major group order keeps
//   the V panels L2-resident. No per-block squaring (r5's VALU wall gone).
// ---------------------------------------------------------------------------
__global__ __launch_bounds__(256) void apply_partial_kernel(
    const unsigned short* __restrict__ P, const unsigned short* __restrict__ VhT,
    const unsigned short* __restrict__ V2hT, const unsigned short* __restrict__ V2lT,
    float* __restrict__ accm_p, float* __restrict__ acc2_p)
{
    __shared__ __align__(16) unsigned short P_s[128 * 32];
    __shared__ __align__(16) unsigned short Vh_s[64 * 32];
    __shared__ __align__(16) unsigned short V2h_s[64 * 32];
    __shared__ __align__(16) unsigned short V2l_s[64 * 32];
    const int tid = threadIdx.x;
    // decode: bid = (group-local j)*8 + xcd; j = glocal*8 + cblk
    const int bid = blockIdx.x;
    const int xcd = bid & 7, j = bid >> 3;            // j: 0..127
    const int c0 = (j & 7) * 64;                      // 8 c-blocks per group
    const int gl = j >> 3;                            // group-local: 0..15
    const int z  = gl >> 2;                           // 4 consecutive groups share z
    const int n0 = (xcd * 4 + (gl & 3)) * 128;        // XCD owns n-rows 4x..4x+3
    const int w = tid >> 6, lane = tid & 63;
    const int wrow = w >> 1, wcol = w & 1;
    const int lr = lane & 15, q = lane >> 4;
    const int srow = lane >> 2, scol = (lane & 3) * 8;
    f32x4 accm[4][2], acc2[4][2];
    #pragma unroll
    for (int i = 0; i < 4; ++i)
        #pragma unroll
        for (int j2 = 0; j2 < 2; ++j2) {
            accm[i][j2] = (f32x4){0.f, 0.f, 0.f, 0.f};
            acc2[i][j2] = (f32x4){0.f, 0.f, 0.f, 0.f};
        }

    const int mbeg = z * (M / MSPLIT);
    const size_t vrow = (size_t)(c0 + w * 16 + srow) * M + scol;
    for (int mc = mbeg; mc < mbeg + M / MSPLIT; mc += 32) {
        __syncthreads();
        #pragma unroll
        for (int g2 = 0; g2 < 2; ++g2) {
            int g = w * 2 + g2;                          // P chunk 0..7
            gload16(&P[(size_t)(n0 + g * 16 + srow) * M + mc + scol], &P_s[g * 512]);
        }
        gload16(&VhT [vrow + mc], &Vh_s[w * 512]);
        gload16(&V2hT[vrow + mc], &V2h_s[w * 512]);
        gload16(&V2lT[vrow + mc], &V2l_s[w * 512]);
        __syncthreads();
        short8 a[4], bh[2], b2h[2], b2l[2];
        #pragma unroll
        for (int i = 0; i < 4; ++i)
            a[i] = *(const short8*)&P_s[(wrow * 64 + i * 16 + lr) * 32 + q * 8];
        #pragma unroll
        for (int j2 = 0; j2 < 2; ++j2) {
            int off = (wcol * 32 + j2 * 16 + lr) * 32 + q * 8;
            bh[j2]  = *(const short8*)&Vh_s[off];
            b2h[j2] = *(const short8*)&V2h_s[off];
            b2l[j2] = *(const short8*)&V2l_s[off];
        }
        #pragma unroll
        for (int i = 0; i < 4; ++i)
            #pragma unroll
            for (int j2 = 0; j2 < 2; ++j2) {
                accm[i][j2] = mfma_bf16(a[i], bh[j2],  accm[i][j2]);
                acc2[i][j2] = mfma_bf16(a[i], b2h[j2], acc2[i][j2]);
                acc2[i][j2] = mfma_bf16(a[i], b2l[j2], acc2[i][j2]);
            }
    }
    const size_t pbase = (size_t)z * N * C;
    #pragma unroll
    for (int i = 0; i < 4; ++i) {
        int nb = n0 + wrow * 64 + i * 16 + q * 4;
        #pragma unroll
        for (int j2 = 0; j2 < 2; ++j2) {
            int c = c0 + wcol * 32 + j2 * 16 + lr;
            #pragma unroll
            for (int r = 0; r < 4; ++r) {
                size_t off = pbase + (size_t)(nb + r) * C + c;
                accm_p[off] = accm[i][j2][r];
                acc2_p[off] = acc2[i][j2][r];
            }
        }
    }
}

// ---------------------------------------------------------------------------
// K4b: combine partials -> mean/std (fp32). One float4 of c per thread.
// ---------------------------------------------------------------------------
__global__ __launch_bounds__(256) void combine_kernel(
    const float* __restrict__ accm_p, const float* __restrict__ acc2_p,
    const float* __restrict__ rsum, float* __restrict__ meanw,
    float* __restrict__ stdw)
{
    const size_t idx = ((size_t)blockIdx.x * 256 + threadIdx.x) * 4;
    const int n = (int)(idx >> 9);        // /C (C=512)
    const float inv = 1.0f / rsum[n];
    float sm[4] = {0.f, 0.f, 0.f, 0.f}, s2[4] = {0.f, 0.f, 0.f, 0.f};
    #pragma unroll
    for (int z = 0; z < MSPLIT; ++z) {
        float4 a = *(const float4*)&accm_p[(size_t)z * N * C + idx];
        float4 b = *(const float4*)&acc2_p[(size_t)z * N * C + idx];
        sm[0] += a.x; sm[1] += a.y; sm[2] += a.z; sm[3] += a.w;
        s2[0] += b.x; s2[1] += b.y; s2[2] += b.z; s2[3] += b.w;
    }
    float4 mnv, sdv;
    float* mp = (float*)&mnv;
    float* sp = (float*)&sdv;
    #pragma unroll
    for (int k = 0; k < 4; ++k) {
        float mn = sm[k] * inv;
        float m2 = s2[k] * inv;
        mp[k] = mn;
        sp[k] = sqrtf(fmaxf(m2 - mn * mn, 0.f));
    }
    *(float4*)&meanw[idx] = mnv;
    *(float4*)&stdw[idx]  = sdv;
}

// ---------------------------------------------------------------------------
// K5: instance-norm stats per channel (fp32)
// ---------------------------------------------------------------------------
__global__ __launch_bounds__(256) void mvn_kernel(
    const float* __restrict__ content, float* __restrict__ mu, float* __restrict__ rstd)
{
    const int c = blockIdx.x;
    const int tid = threadIdx.x;
    const float* row = content + (size_t)c * N;
    float s = 0.f, ss = 0.f;
    for (int i = tid; i < N; i += 256) {
        float v = row[i];
        s += v;
        ss = fmaf(v, v, ss);
    }
    #pragma unroll
    for (int off = 32; off > 0; off >>= 1) {
        s  += __shfl_xor(s,  off, 64);
        ss += __shfl_xor(ss, off, 64);
    }
    __shared__ float rs[4], rss[4];
    const int wid = tid >> 6, lane = tid & 63;
    if (lane == 0) { rs[wid] = s; rss[wid] = ss; }
    __syncthreads();
    if (tid == 0) {
        float st = rs[0] + rs[1] + rs[2] + rs[3];
        float sst = rss[0] + rss[1] + rss[2] + rss[3];
        float m = st / (float)N;
        float var = (sst - st * st / (float)N) / (float)(N - 1);
        mu[c] = m;
        rstd[c] = rsqrtf(var + 1e-5f);
    }
}

// ---------------------------------------------------------------------------
// K6: final combine (fp32)
// ---------------------------------------------------------------------------
__global__ __launch_bounds__(256) void final_kernel(
    const float* __restrict__ content, const float* __restrict__ meanw,
    const float* __restrict__ stdw, const float* __restrict__ mu,
    const float* __restrict__ rstd, float* __restrict__ out)
{
    __shared__ float mn_s[32][33], sd_s[32][33];
    const int tid = threadIdx.x;
    const int n0 = blockIdx.x * 32;
    const int c0 = blockIdx.y * 32;
    const int tx = tid & 31, ty = tid >> 5;
    #pragma unroll
    for (int i = 0; i < 4; ++i) {
        int n = ty + i * 8;
        mn_s[tx][n] = meanw[(size_t)(n0 + n) * C + c0 + tx];
        sd_s[tx][n] = stdw [(size_t)(n0 + n) * C + c0 + tx];
    }
    __syncthreads();
    #pragma unroll
    for (int i = 0; i < 4; ++i) {
        int c = ty + i * 8;
        float m = mu[c0 + c], r = rstd[c0 + c];
        size_t off = (size_t)(c0 + c) * N + n0 + tx;
        float x = content[off];
        out[off] = sd_s[c][tx] * (x - m) * r + mn_s[c][tx];
    }
}

// ---------------------------------------------------------------------------
extern "C" void kernel_launch(void* const* d_in, const int* in_sizes, int n_in,
                              void* d_out, int out_size, void* d_ws, size_t ws_size,
                              hipStream_t stream)
{
    const float* content = (const float*)d_in[0];
    const float* style   = (const float*)d_in[1];
    const float* ckey    = (const float*)d_in[2];
    const float* skey    = (const float*)d_in[3];
    const float* Wf      = (const float*)d_in[4];
    const float* bf      = (const float*)d_in[5];
    const float* Wg      = (const float*)d_in[6];
    const float* bg      = (const float*)d_in[7];
    const float* Wh      = (const float*)d_in[8];
    const float* bh      = (const float*)d_in[9];
    float* out = (float*)d_out;

    const size_t sz_w  = (size_t)512 * 512 * 2;      // one W half
    const size_t sz_S  = (size_t)N * M * 4;          // 64 MB (aliased by partials)
    const size_t sz_FG = (size_t)N * C * 2;
    const size_t sz_P  = (size_t)N * M * 2;
    const size_t sz_V  = (size_t)C * M * 2;

    char* p = (char*)d_ws;
    auto alloc = [&](size_t bytes) {
        char* r = p;
        p += (bytes + 255) & ~(size_t)255;
        return r;
    };
    unsigned short* WfH = (unsigned short*)alloc(sz_w);
    unsigned short* WfL = (unsigned short*)alloc(sz_w);
    unsigned short* WgH = (unsigned short*)alloc(sz_w);
    unsigned short* WgL = (unsigned short*)alloc(sz_w);
    unsigned short* WhH = (unsigned short*)alloc(sz_w);
    unsigned short* WhL = (unsigned short*)alloc(sz_w);
    float* S = (float*)alloc(sz_S);                  // also: partial accm/acc2
    unsigned short* Fh = (unsigned short*)alloc(sz_FG);
    unsigned short* Fl = (unsigned short*)alloc(sz_FG);
    unsigned short* Gh = (unsigned short*)alloc(sz_FG);
    unsigned short* Gl = (unsigned short*)alloc(sz_FG);
    unsigned short* P    = (unsigned short*)alloc(sz_P);
    unsigned short* VhT  = (unsigned short*)alloc(sz_V);
    unsigned short* V2hT = (unsigned short*)alloc(sz_V);
    unsigned short* V2lT = (unsigned short*)alloc(sz_V);
    float* rsum  = (float*)alloc((size_t)N * 4);
    float* meanw = (float*)alloc((size_t)N * C * 4);
    float* stdw  = (float*)alloc((size_t)N * C * 4);
    float* mu    = (float*)alloc((size_t)C * 4);
    float* rstd  = (float*)alloc((size_t)C * 4);

    // partials alias S (dead between rowstat and next batch's logits):
    // accm_p = MSPLIT*N*C floats, acc2_p = MSPLIT*N*C floats = exactly N*M
    float* accm_p = S;
    float* acc2_p = S + (size_t)MSPLIT * N * C;

    wsplit_kernel<<<dim3(1024), 256, 0, stream>>>(Wf, WfH, WfL);
    wsplit_kernel<<<dim3(1024), 256, 0, stream>>>(Wg, WgH, WgL);
    wsplit_kernel<<<dim3(1024), 256, 0, stream>>>(Wh, WhH, WhL);

    for (int b = 0; b < BATCH; ++b) {
        const size_t fo = (size_t)b * C * N;
        linear_fg_mfma<<<dim3(N / 64, C / 64), 256, 0, stream>>>(ckey + fo, WfH, WfL, bf, Fh, Fl);
        linear_fg_mfma<<<dim3(M / 64, C / 64), 256, 0, stream>>>(skey + fo, WgH, WgL, bg, Gh, Gl);
        linear_v_mfma<<<dim3(M / 64, C / 64), 256, 0, stream>>>(style + fo, WhH, WhL, bh,
                                                                VhT, V2hT, V2lT);
        logits_mfma_kernel<<<dim3(M / 128, N / 128), 256, 0, stream>>>(Fh, Fl, Gh, Gl, S);
        rowstat_p_kernel<<<dim3(N), 256, 0, stream>>>(S, P, rsum);
        apply_partial_kernel<<<dim3(1024), 256, 0, stream>>>(
            P, VhT, V2hT, V2lT, accm_p, acc2_p);
        combine_kernel<<<dim3(N * C / 1024), 256, 0, stream>>>(
            accm_p, acc2_p, rsum, meanw, stdw);
        mvn_kernel<<<dim3(C), 256, 0, stream>>>(content + fo, mu, rstd);
        final_kernel<<<dim3(N / 32, C / 32), 256, 0, stream>>>(
            content + fo, meanw, stdw, mu, rstd, out + fo);
    }
}